// Round 1
// baseline (2804.454 us; speedup 1.0000x reference)
//
#include <hip/hip_runtime.h>
#include <math.h>

#define B_   2
#define S_   2048
#define DM_  1024
#define NH_  16
#define DH_  64
#define DFF_ 4096
#define WIN_ 256
#define MTOK (B_*S_)   // 4096 tokens

// ---------------------------------------------------------------------------
// Generic f32 GEMM: C[M,N] = act(A[M,K] @ W[K,N] + bias[N]) (+ res[M,N])
// 64x64 tile, BK=16, 256 threads, 4x4 accumulators per thread.
// M%64==0, N%64==0, K%16==0 guaranteed by problem dims.
// act: 0 = none, 1 = exact GELU (erf).
// ---------------------------------------------------------------------------
#define BM 64
#define BN 64
#define BK 16

__device__ __forceinline__ float gelu_exact(float x) {
    return 0.5f * x * (1.0f + erff(x * 0.70710678118654752f));
}

__global__ __launch_bounds__(256) void gemm_bias(
    const float* __restrict__ A, const float* __restrict__ W,
    const float* __restrict__ bias, const float* __restrict__ res,
    float* __restrict__ C, int M, int N, int K, int act)
{
    __shared__ float As[BK][BM];   // [kk][row]
    __shared__ float Bs[BK][BN];   // [kk][col]

    const int tid = threadIdx.x;
    const int bx = blockIdx.x;     // N tiles
    const int by = blockIdx.y;     // M tiles
    const int tx = tid & 15;
    const int ty = tid >> 4;
    const int row0 = by * BM + ty * 4;
    const int col0 = bx * BN + tx * 4;

    // A staging: thread loads float4 along K. arow in [0,64), akk in {0,4,8,12}
    const int arow = tid >> 2;
    const int akk  = (tid & 3) * 4;
    // B staging: thread loads float4 along N. bkk in [0,16), bcol in {0,4,...,60}
    const int bkk  = tid >> 4;
    const int bcol = (tid & 15) * 4;

    const float* Abase = A + (size_t)(by * BM + arow) * K + akk;
    const float* Wcol  = W + (size_t)bx * BN + bcol;

    float acc[4][4] = {};

    for (int k0 = 0; k0 < K; k0 += BK) {
        float4 av = *(const float4*)(Abase + k0);
        float4 wv = *(const float4*)(Wcol + (size_t)(k0 + bkk) * N);
        __syncthreads();   // protect previous iteration's LDS reads
        As[akk + 0][arow] = av.x;
        As[akk + 1][arow] = av.y;
        As[akk + 2][arow] = av.z;
        As[akk + 3][arow] = av.w;
        *(float4*)&Bs[bkk][bcol] = wv;
        __syncthreads();
        #pragma unroll
        for (int kk = 0; kk < BK; ++kk) {
            float4 a4 = *(const float4*)&As[kk][ty * 4];
            float4 b4 = *(const float4*)&Bs[kk][tx * 4];
            const float aa[4] = {a4.x, a4.y, a4.z, a4.w};
            const float bb[4] = {b4.x, b4.y, b4.z, b4.w};
            #pragma unroll
            for (int i = 0; i < 4; ++i)
                #pragma unroll
                for (int j = 0; j < 4; ++j)
                    acc[i][j] = fmaf(aa[i], bb[j], acc[i][j]);
        }
    }

    #pragma unroll
    for (int i = 0; i < 4; ++i) {
        #pragma unroll
        for (int j = 0; j < 4; ++j) {
            float v = acc[i][j] + bias[col0 + j];
            if (act == 1) v = gelu_exact(v);
            size_t idx = (size_t)(row0 + i) * N + (col0 + j);
            if (res) v += res[idx];
            C[idx] = v;
        }
    }
}

// ---------------------------------------------------------------------------
// Per-head LayerNorm over DH=64: one wave per (b,s,h) vector, in place.
// ---------------------------------------------------------------------------
__global__ __launch_bounds__(256) void ln_head(
    float* __restrict__ t, const float* __restrict__ g, const float* __restrict__ b)
{
    const int gw   = (blockIdx.x * 256 + threadIdx.x) >> 6;   // vector index
    const int lane = threadIdx.x & 63;
    const size_t base = (size_t)gw * 64 + lane;
    float v = t[base];
    float s = v;
    #pragma unroll
    for (int o = 32; o >= 1; o >>= 1) s += __shfl_xor(s, o);
    const float mean = s * (1.0f / 64.0f);
    const float d = v - mean;
    float s2 = d * d;
    #pragma unroll
    for (int o = 32; o >= 1; o >>= 1) s2 += __shfl_xor(s2, o);
    const float var = s2 * (1.0f / 64.0f);
    t[base] = d * rsqrtf(var + 1e-5f) * g[lane] + b[lane];
}

// ---------------------------------------------------------------------------
// Windowed causal attention: one wave per (b, h, i). Lane = head dim.
// Online softmax over j in [max(0,i-WIN), i].
// ---------------------------------------------------------------------------
__global__ __launch_bounds__(256) void attn_win(
    const float* __restrict__ q, const float* __restrict__ k,
    const float* __restrict__ v, float* __restrict__ o)
{
    const int gw   = (blockIdx.x * 256 + threadIdx.x) >> 6;
    const int lane = threadIdx.x & 63;
    const int i = gw % S_;
    const int h = (gw / S_) % NH_;
    const int b = gw / (S_ * NH_);

    const float qd = q[(((size_t)b * S_ + i) * NH_ + h) * DH_ + lane];
    float M = -INFINITY, L = 0.0f, acc = 0.0f;
    const int j0 = (i - WIN_) > 0 ? (i - WIN_) : 0;
    for (int j = j0; j <= i; ++j) {
        const size_t idx = (((size_t)b * S_ + j) * NH_ + h) * DH_ + lane;
        float p = qd * k[idx];
        #pragma unroll
        for (int off = 32; off >= 1; off >>= 1) p += __shfl_xor(p, off);
        const float sc = p * 0.125f;               // 1/sqrt(64)
        const float nM = fmaxf(M, sc);
        const float alpha = __expf(M - nM);        // 0 on first iter (M=-inf)
        const float e = __expf(sc - nM);
        L = L * alpha + e;
        acc = acc * alpha + e * v[idx];
        M = nM;
    }
    o[(((size_t)b * S_ + i) * NH_ + h) * DH_ + lane] = acc / L;
}

// ---------------------------------------------------------------------------
// Token LayerNorm over N (1024 or 4096): one block (256 thr) per token.
// ---------------------------------------------------------------------------
template <int N>
__global__ __launch_bounds__(256) void ln_token(
    const float* __restrict__ in, float* __restrict__ outp,
    const float* __restrict__ g, const float* __restrict__ b)
{
    constexpr int NPT = N / 256;
    const int t = blockIdx.x;
    const float* row = in + (size_t)t * N;
    float vals[NPT];
    float s = 0.0f, s2 = 0.0f;
    #pragma unroll
    for (int i = 0; i < NPT; ++i) {
        float x = row[i * 256 + threadIdx.x];
        vals[i] = x;
        s += x;
        s2 = fmaf(x, x, s2);
    }
    #pragma unroll
    for (int o = 32; o >= 1; o >>= 1) { s += __shfl_xor(s, o); s2 += __shfl_xor(s2, o); }
    __shared__ float rs[4], rq[4];
    const int wid = threadIdx.x >> 6, lane = threadIdx.x & 63;
    if (lane == 0) { rs[wid] = s; rq[wid] = s2; }
    __syncthreads();
    s  = rs[0] + rs[1] + rs[2] + rs[3];
    s2 = rq[0] + rq[1] + rq[2] + rq[3];
    const float mean = s * (1.0f / N);
    const float var  = s2 * (1.0f / N) - mean * mean;
    const float rstd = rsqrtf(var + 1e-5f);
    #pragma unroll
    for (int i = 0; i < NPT; ++i) {
        const int idx = i * 256 + threadIdx.x;
        outp[(size_t)t * N + idx] = (vals[i] - mean) * rstd * g[idx] + b[idx];
    }
}

// ---------------------------------------------------------------------------
// Final combine: out = h + base*wm + adaptive*(1-wm), adaptive routed by widx.
// base lives in d_out (written by fc2 GEMM).
// ---------------------------------------------------------------------------
__global__ __launch_bounds__(256) void combine(
    float* __restrict__ outp, const float* __restrict__ h,
    const float* __restrict__ xn, const float* __restrict__ a0,
    const float* __restrict__ a1, const float* __restrict__ wm,
    const int* __restrict__ widx)
{
    const size_t idx = (size_t)blockIdx.x * 256 + threadIdx.x;
    const int t = (int)(idx >> 10);           // /DM_
    const float w = wm[t];
    const int sel = widx[t];
    const float ad = (sel == 0) ? a0[idx] : ((sel == 1) ? a1[idx] : xn[idx]);
    outp[idx] = h[idx] + outp[idx] * w + ad * (1.0f - w);
}

// ---------------------------------------------------------------------------
extern "C" void kernel_launch(void* const* d_in, const int* in_sizes, int n_in,
                              void* d_out, int out_size, void* d_ws, size_t ws_size,
                              hipStream_t stream)
{
    const float* x     = (const float*)d_in[0];
    const float* wm    = (const float*)d_in[1];
    const float* wq    = (const float*)d_in[2];
    const float* bq    = (const float*)d_in[3];
    const float* wk    = (const float*)d_in[4];
    const float* bk    = (const float*)d_in[5];
    const float* wv    = (const float*)d_in[6];
    const float* bv    = (const float*)d_in[7];
    const float* wo    = (const float*)d_in[8];
    const float* bo    = (const float*)d_in[9];
    const float* lnq_g = (const float*)d_in[10];
    const float* lnq_b = (const float*)d_in[11];
    const float* lnk_g = (const float*)d_in[12];
    const float* lnk_b = (const float*)d_in[13];
    const float* fc1_w = (const float*)d_in[14];
    const float* fc1_b = (const float*)d_in[15];
    const float* fc2_w = (const float*)d_in[16];
    const float* fc2_b = (const float*)d_in[17];
    const float* lni_g = (const float*)d_in[18];
    const float* lni_b = (const float*)d_in[19];
    const float* lnh_g = (const float*)d_in[20];
    const float* lnh_b = (const float*)d_in[21];
    const float* a256_w1 = (const float*)d_in[22];
    const float* a256_b1 = (const float*)d_in[23];
    const float* a256_w2 = (const float*)d_in[24];
    const float* a256_b2 = (const float*)d_in[25];
    const float* a512_w1 = (const float*)d_in[26];
    const float* a512_b1 = (const float*)d_in[27];
    const float* a512_w2 = (const float*)d_in[28];
    const float* a512_b2 = (const float*)d_in[29];
    const int*   widx    = (const int*)d_in[30];

    float* out = (float*)d_out;
    float* ws  = (float*)d_ws;

    const size_t tokDM = (size_t)MTOK * DM_;
    float* q    = ws;
    float* kbuf = q    + tokDM;
    float* vbuf = kbuf + tokDM;
    float* attn = vbuf + tokDM;
    float* hbuf = attn + tokDM;
    float* hid  = hbuf + tokDM;          // MTOK * DFF_
    // aliases (lifetimes verified): xn<-q, a0<-attn, a1<-k, adapter tmp<-v
    float* xn = q;
    float* a0 = attn;
    float* a1 = kbuf;
    float* tA = vbuf;

    const dim3 blk(256);
    auto grid = [](int M, int N) { return dim3(N / BN, M / BM); };

    // QKV projections
    gemm_bias<<<grid(MTOK, DM_), blk, 0, stream>>>(x, wq, bq, nullptr, q,    MTOK, DM_, DM_, 0);
    gemm_bias<<<grid(MTOK, DM_), blk, 0, stream>>>(x, wk, bk, nullptr, kbuf, MTOK, DM_, DM_, 0);
    gemm_bias<<<grid(MTOK, DM_), blk, 0, stream>>>(x, wv, bv, nullptr, vbuf, MTOK, DM_, DM_, 0);

    // per-head LN on q, k (65536 waves / 4 per block)
    ln_head<<<MTOK * NH_ / 4, blk, 0, stream>>>(q,    lnq_g, lnq_b);
    ln_head<<<MTOK * NH_ / 4, blk, 0, stream>>>(kbuf, lnk_g, lnk_b);

    // windowed causal attention
    attn_win<<<MTOK * NH_ / 4, blk, 0, stream>>>(q, kbuf, vbuf, attn);

    // output projection + residual
    gemm_bias<<<grid(MTOK, DM_), blk, 0, stream>>>(attn, wo, bo, x, hbuf, MTOK, DM_, DM_, 0);

    // FFN input LN
    ln_token<DM_><<<MTOK, blk, 0, stream>>>(hbuf, xn, lni_g, lni_b);

    // base FFN
    gemm_bias<<<grid(MTOK, DFF_), blk, 0, stream>>>(xn, fc1_w, fc1_b, nullptr, hid, MTOK, DFF_, DM_, 1);
    ln_token<DFF_><<<MTOK, blk, 0, stream>>>(hid, hid, lnh_g, lnh_b);
    gemm_bias<<<grid(MTOK, DM_), blk, 0, stream>>>(hid, fc2_w, fc2_b, nullptr, out, MTOK, DM_, DFF_, 0);

    // adapters
    gemm_bias<<<grid(MTOK, 256), blk, 0, stream>>>(xn, a256_w1, a256_b1, nullptr, tA, MTOK, 256, DM_, 1);
    gemm_bias<<<grid(MTOK, DM_), blk, 0, stream>>>(tA, a256_w2, a256_b2, nullptr, a0, MTOK, DM_, 256, 0);
    gemm_bias<<<grid(MTOK, 512), blk, 0, stream>>>(xn, a512_w1, a512_b1, nullptr, tA, MTOK, 512, DM_, 1);
    gemm_bias<<<grid(MTOK, DM_), blk, 0, stream>>>(tA, a512_w2, a512_b2, nullptr, a1, MTOK, DM_, 512, 0);

    // final routed combine
    combine<<<(int)(tokDM / 256), blk, 0, stream>>>(out, hbuf, xn, a0, a1, wm, widx);
}

// Round 2
// 1986.026 us; speedup vs baseline: 1.4121x; 1.4121x over previous
//
#include <hip/hip_runtime.h>
#include <math.h>

#define B_   2
#define S_   2048
#define DM_  1024
#define NH_  16
#define DH_  64
#define DFF_ 4096
#define WIN_ 256
#define MTOK (B_*S_)   // 4096 tokens

// ---------------------------------------------------------------------------
// Generic f32 GEMM: C[M,N] = act(A[M,K] @ W[K,N] + bias[N]) (+ res[M,N])
// 64x64 tile, BK=16, 256 threads, 4x4 accumulators per thread.
// ---------------------------------------------------------------------------
#define BM 64
#define BN 64
#define BK 16

__device__ __forceinline__ float gelu_exact(float x) {
    return 0.5f * x * (1.0f + erff(x * 0.70710678118654752f));
}

__global__ __launch_bounds__(256) void gemm_bias(
    const float* __restrict__ A, const float* __restrict__ W,
    const float* __restrict__ bias, const float* __restrict__ res,
    float* __restrict__ C, int M, int N, int K, int act)
{
    __shared__ float As[BK][BM];   // [kk][row]
    __shared__ float Bs[BK][BN];   // [kk][col]

    const int tid = threadIdx.x;
    const int bx = blockIdx.x;     // N tiles
    const int by = blockIdx.y;     // M tiles
    const int tx = tid & 15;
    const int ty = tid >> 4;
    const int row0 = by * BM + ty * 4;
    const int col0 = bx * BN + tx * 4;

    const int arow = tid >> 2;
    const int akk  = (tid & 3) * 4;
    const int bkk  = tid >> 4;
    const int bcol = (tid & 15) * 4;

    const float* Abase = A + (size_t)(by * BM + arow) * K + akk;
    const float* Wcol  = W + (size_t)bx * BN + bcol;

    float acc[4][4] = {};

    for (int k0 = 0; k0 < K; k0 += BK) {
        float4 av = *(const float4*)(Abase + k0);
        float4 wv = *(const float4*)(Wcol + (size_t)(k0 + bkk) * N);
        __syncthreads();
        As[akk + 0][arow] = av.x;
        As[akk + 1][arow] = av.y;
        As[akk + 2][arow] = av.z;
        As[akk + 3][arow] = av.w;
        *(float4*)&Bs[bkk][bcol] = wv;
        __syncthreads();
        #pragma unroll
        for (int kk = 0; kk < BK; ++kk) {
            float4 a4 = *(const float4*)&As[kk][ty * 4];
            float4 b4 = *(const float4*)&Bs[kk][tx * 4];
            const float aa[4] = {a4.x, a4.y, a4.z, a4.w};
            const float bb[4] = {b4.x, b4.y, b4.z, b4.w};
            #pragma unroll
            for (int i = 0; i < 4; ++i)
                #pragma unroll
                for (int j = 0; j < 4; ++j)
                    acc[i][j] = fmaf(aa[i], bb[j], acc[i][j]);
        }
    }

    #pragma unroll
    for (int i = 0; i < 4; ++i) {
        #pragma unroll
        for (int j = 0; j < 4; ++j) {
            float v = acc[i][j] + bias[col0 + j];
            if (act == 1) v = gelu_exact(v);
            size_t idx = (size_t)(row0 + i) * N + (col0 + j);
            if (res) v += res[idx];
            C[idx] = v;
        }
    }
}

// ---------------------------------------------------------------------------
// Per-head LayerNorm over DH=64: one wave per (b,s,h) vector, in place.
// ---------------------------------------------------------------------------
__global__ __launch_bounds__(256) void ln_head(
    float* __restrict__ t, const float* __restrict__ g, const float* __restrict__ b)
{
    const int gw   = (blockIdx.x * 256 + threadIdx.x) >> 6;
    const int lane = threadIdx.x & 63;
    const size_t base = (size_t)gw * 64 + lane;
    float v = t[base];
    float s = v;
    #pragma unroll
    for (int o = 32; o >= 1; o >>= 1) s += __shfl_xor(s, o);
    const float mean = s * (1.0f / 64.0f);
    const float d = v - mean;
    float s2 = d * d;
    #pragma unroll
    for (int o = 32; o >= 1; o >>= 1) s2 += __shfl_xor(s2, o);
    const float var = s2 * (1.0f / 64.0f);
    t[base] = d * rsqrtf(var + 1e-5f) * g[lane] + b[lane];
}

// ---------------------------------------------------------------------------
// Windowed causal attention v2: one wave per 16 queries.
// lane = (qi = lane&15, dg = lane>>4): lane owns query i0+qi, dims dg*16..+15.
// Q row and output acc live in registers for the whole window; per key:
// 16 score FMAs + 2 shfl_xor (cross d-group reduce) + per-lane softmax state.
// K/V rows are broadcast loads (16 lanes share addr) — L1/L2 resident.
// ---------------------------------------------------------------------------
__global__ __launch_bounds__(256) void attn_win2(
    const float* __restrict__ q, const float* __restrict__ k,
    const float* __restrict__ v, float* __restrict__ o)
{
    const int wid  = (blockIdx.x * 256 + threadIdx.x) >> 6;   // global wave
    const int lane = threadIdx.x & 63;
    const int qi = lane & 15;
    const int dg = lane >> 4;
    const int qt = wid & 127;            // S/16 = 128 query tiles
    const int h  = (wid >> 7) & 15;
    const int b  = wid >> 11;
    const int i  = qt * 16 + qi;         // this lane's query index

    const size_t rowstride = (size_t)DH_;                  // within token*NH
    const size_t qbase = (((size_t)b * S_ + i) * NH_ + h) * DH_ + dg * 16;

    float qr[16];
    #pragma unroll
    for (int t = 0; t < 4; ++t)
        *(float4*)&qr[t * 4] = *(const float4*)(q + qbase + t * 4);

    float acc[16] = {};
    float M = -1e30f, L = 0.0f;

    const int i0  = qt * 16;
    const int jlo = (i0 - WIN_) > 0 ? (i0 - WIN_) : 0;
    const int jhi = i0 + 15;

    #pragma unroll 2
    for (int j = jlo; j <= jhi; ++j) {
        const size_t kb = (((size_t)b * S_ + j) * NH_ + h) * rowstride + dg * 16;
        float kr[16], vr[16];
        #pragma unroll
        for (int t = 0; t < 4; ++t) {
            *(float4*)&kr[t * 4] = *(const float4*)(k + kb + t * 4);
            *(float4*)&vr[t * 4] = *(const float4*)(v + kb + t * 4);
        }
        float s = 0.0f;
        #pragma unroll
        for (int t = 0; t < 16; ++t) s = fmaf(qr[t], kr[t], s);
        s += __shfl_xor(s, 16);
        s += __shfl_xor(s, 32);
        s *= 0.125f;                                   // 1/sqrt(64)
        const bool ok = (j <= i) && ((i - j) <= WIN_);
        s = ok ? s : -1e30f;
        const float nM = fmaxf(M, s);
        const float alpha = __expf(M - nM);            // 1 while nothing seen
        const float e = ok ? __expf(s - nM) : 0.0f;
        L = L * alpha + e;
        #pragma unroll
        for (int t = 0; t < 16; ++t)
            acc[t] = fmaf(acc[t], alpha, e * vr[t]);
        M = nM;
    }

    const float inv = 1.0f / L;
    float outv[16];
    #pragma unroll
    for (int t = 0; t < 16; ++t) outv[t] = acc[t] * inv;
    #pragma unroll
    for (int t = 0; t < 4; ++t)
        *(float4*)(o + qbase + t * 4) = *(const float4*)&outv[t * 4];
}

// ---------------------------------------------------------------------------
// Token LayerNorm over N (1024 or 4096): one block (256 thr) per token.
// ---------------------------------------------------------------------------
template <int N>
__global__ __launch_bounds__(256) void ln_token(
    const float* __restrict__ in, float* __restrict__ outp,
    const float* __restrict__ g, const float* __restrict__ b)
{
    constexpr int NPT = N / 256;
    const int t = blockIdx.x;
    const float* row = in + (size_t)t * N;
    float vals[NPT];
    float s = 0.0f, s2 = 0.0f;
    #pragma unroll
    for (int i = 0; i < NPT; ++i) {
        float x = row[i * 256 + threadIdx.x];
        vals[i] = x;
        s += x;
        s2 = fmaf(x, x, s2);
    }
    #pragma unroll
    for (int o = 32; o >= 1; o >>= 1) { s += __shfl_xor(s, o); s2 += __shfl_xor(s2, o); }
    __shared__ float rs[4], rq[4];
    const int wid = threadIdx.x >> 6, lane = threadIdx.x & 63;
    if (lane == 0) { rs[wid] = s; rq[wid] = s2; }
    __syncthreads();
    s  = rs[0] + rs[1] + rs[2] + rs[3];
    s2 = rq[0] + rq[1] + rq[2] + rq[3];
    const float mean = s * (1.0f / N);
    const float var  = s2 * (1.0f / N) - mean * mean;
    const float rstd = rsqrtf(var + 1e-5f);
    #pragma unroll
    for (int i = 0; i < NPT; ++i) {
        const int idx = i * 256 + threadIdx.x;
        outp[(size_t)t * N + idx] = (vals[i] - mean) * rstd * g[idx] + b[idx];
    }
}

// ---------------------------------------------------------------------------
// Final combine: out = h + base*wm + adaptive*(1-wm), adaptive routed by widx.
// ---------------------------------------------------------------------------
__global__ __launch_bounds__(256) void combine(
    float* __restrict__ outp, const float* __restrict__ h,
    const float* __restrict__ xn, const float* __restrict__ a0,
    const float* __restrict__ a1, const float* __restrict__ wm,
    const int* __restrict__ widx)
{
    const size_t idx = (size_t)blockIdx.x * 256 + threadIdx.x;
    const int t = (int)(idx >> 10);           // /DM_
    const float w = wm[t];
    const int sel = widx[t];
    const float ad = (sel == 0) ? a0[idx] : ((sel == 1) ? a1[idx] : xn[idx]);
    outp[idx] = h[idx] + outp[idx] * w + ad * (1.0f - w);
}

// ---------------------------------------------------------------------------
extern "C" void kernel_launch(void* const* d_in, const int* in_sizes, int n_in,
                              void* d_out, int out_size, void* d_ws, size_t ws_size,
                              hipStream_t stream)
{
    const float* x     = (const float*)d_in[0];
    const float* wm    = (const float*)d_in[1];
    const float* wq    = (const float*)d_in[2];
    const float* bq    = (const float*)d_in[3];
    const float* wk    = (const float*)d_in[4];
    const float* bk    = (const float*)d_in[5];
    const float* wv    = (const float*)d_in[6];
    const float* bv    = (const float*)d_in[7];
    const float* wo    = (const float*)d_in[8];
    const float* bo    = (const float*)d_in[9];
    const float* lnq_g = (const float*)d_in[10];
    const float* lnq_b = (const float*)d_in[11];
    const float* lnk_g = (const float*)d_in[12];
    const float* lnk_b = (const float*)d_in[13];
    const float* fc1_w = (const float*)d_in[14];
    const float* fc1_b = (const float*)d_in[15];
    const float* fc2_w = (const float*)d_in[16];
    const float* fc2_b = (const float*)d_in[17];
    const float* lni_g = (const float*)d_in[18];
    const float* lni_b = (const float*)d_in[19];
    const float* lnh_g = (const float*)d_in[20];
    const float* lnh_b = (const float*)d_in[21];
    const float* a256_w1 = (const float*)d_in[22];
    const float* a256_b1 = (const float*)d_in[23];
    const float* a256_w2 = (const float*)d_in[24];
    const float* a256_b2 = (const float*)d_in[25];
    const float* a512_w1 = (const float*)d_in[26];
    const float* a512_b1 = (const float*)d_in[27];
    const float* a512_w2 = (const float*)d_in[28];
    const float* a512_b2 = (const float*)d_in[29];
    const int*   widx    = (const int*)d_in[30];

    float* out = (float*)d_out;
    float* ws  = (float*)d_ws;

    const size_t tokDM = (size_t)MTOK * DM_;
    float* q    = ws;
    float* kbuf = q    + tokDM;
    float* vbuf = kbuf + tokDM;
    float* attn = vbuf + tokDM;
    float* hbuf = attn + tokDM;
    float* hid  = hbuf + tokDM;          // MTOK * DFF_
    float* xn = q;      // aliases, lifetimes verified
    float* a0 = attn;
    float* a1 = kbuf;
    float* tA = vbuf;

    const dim3 blk(256);
    auto grid = [](int M, int N) { return dim3(N / BN, M / BM); };

    // QKV projections
    gemm_bias<<<grid(MTOK, DM_), blk, 0, stream>>>(x, wq, bq, nullptr, q,    MTOK, DM_, DM_, 0);
    gemm_bias<<<grid(MTOK, DM_), blk, 0, stream>>>(x, wk, bk, nullptr, kbuf, MTOK, DM_, DM_, 0);
    gemm_bias<<<grid(MTOK, DM_), blk, 0, stream>>>(x, wv, bv, nullptr, vbuf, MTOK, DM_, DM_, 0);

    // per-head LN on q, k
    ln_head<<<MTOK * NH_ / 4, blk, 0, stream>>>(q,    lnq_g, lnq_b);
    ln_head<<<MTOK * NH_ / 4, blk, 0, stream>>>(kbuf, lnk_g, lnk_b);

    // windowed causal attention v2: B*NH*(S/16) = 4096 waves -> 1024 blocks
    attn_win2<<<B_ * NH_ * (S_ / 16) / 4, blk, 0, stream>>>(q, kbuf, vbuf, attn);

    // output projection + residual
    gemm_bias<<<grid(MTOK, DM_), blk, 0, stream>>>(attn, wo, bo, x, hbuf, MTOK, DM_, DM_, 0);

    // FFN input LN
    ln_token<DM_><<<MTOK, blk, 0, stream>>>(hbuf, xn, lni_g, lni_b);

    // base FFN
    gemm_bias<<<grid(MTOK, DFF_), blk, 0, stream>>>(xn, fc1_w, fc1_b, nullptr, hid, MTOK, DFF_, DM_, 1);
    ln_token<DFF_><<<MTOK, blk, 0, stream>>>(hid, hid, lnh_g, lnh_b);
    gemm_bias<<<grid(MTOK, DM_), blk, 0, stream>>>(hid, fc2_w, fc2_b, nullptr, out, MTOK, DM_, DFF_, 0);

    // adapters
    gemm_bias<<<grid(MTOK, 256), blk, 0, stream>>>(xn, a256_w1, a256_b1, nullptr, tA, MTOK, 256, DM_, 1);
    gemm_bias<<<grid(MTOK, DM_), blk, 0, stream>>>(tA, a256_w2, a256_b2, nullptr, a0, MTOK, DM_, 256, 0);
    gemm_bias<<<grid(MTOK, 512), blk, 0, stream>>>(xn, a512_w1, a512_b1, nullptr, tA, MTOK, 512, DM_, 1);
    gemm_bias<<<grid(MTOK, DM_), blk, 0, stream>>>(tA, a512_w2, a512_b2, nullptr, a1, MTOK, DM_, 512, 0);

    // final routed combine
    combine<<<(int)(tokDM / 256), blk, 0, stream>>>(out, hbuf, xn, a0, a1, wm, widx);
}

// Round 3
// 650.537 us; speedup vs baseline: 4.3110x; 3.0529x over previous
//
#include <hip/hip_runtime.h>
#include <math.h>

#define B_   2
#define S_   2048
#define DM_  1024
#define NH_  16
#define DH_  64
#define DFF_ 4096
#define WIN_ 256
#define MTOK (B_*S_)   // 4096 tokens

typedef unsigned short ushort_t;
typedef short s16x8 __attribute__((ext_vector_type(8)));
typedef float f32x4 __attribute__((ext_vector_type(4)));

__device__ __forceinline__ float b2f(ushort_t u) {
    union { unsigned int i; float f; } c; c.i = ((unsigned int)u) << 16; return c.f;
}
__device__ __forceinline__ ushort_t f2b(float f) {
    union { float f; unsigned int i; } c; c.f = f;
    unsigned int r = c.i + 0x7fffu + ((c.i >> 16) & 1u);   // RNE
    return (ushort_t)(r >> 16);
}
__device__ __forceinline__ float gelu_exact(float x) {
    return 0.5f * x * (1.0f + erff(x * 0.70710678118654752f));
}
__device__ __forceinline__ void gload16(const void* g, void* l) {
    __builtin_amdgcn_global_load_lds(
        (const __attribute__((address_space(1))) unsigned int*)g,
        (__attribute__((address_space(3))) unsigned int*)l, 16, 0, 0);
}

// ---------------------------------------------------------------------------
// bf16 MFMA GEMM (m97 structure): C[M,N] = act(A[M,K] @ Bt[N,K]^T + bias)
// 128x128 tile, BK=64, 4 waves, 16x16x32 MFMA, global_load_lds staging.
// A: bf16 [M,lda]; Bt: bf16 [N,K] (weights pre-transposed); outputs f32/bf16.
// ---------------------------------------------------------------------------
template <int ACT>
__global__ __launch_bounds__(256) void gemm_mfma(
    const ushort_t* __restrict__ A, int lda,
    const ushort_t* __restrict__ Bt,
    const float* __restrict__ bias, const float* __restrict__ res,
    float* __restrict__ Cf, ushort_t* __restrict__ Cb,
    int M, int N, int K)
{
    __shared__ __align__(16) ushort_t As[128 * 64];
    __shared__ __align__(16) ushort_t Bs[128 * 64];

    const int tid  = threadIdx.x;
    const int lane = tid & 63;
    const int w    = tid >> 6;
    const int row0 = blockIdx.y * 128;
    const int col0 = blockIdx.x * 128;

    const int srow = lane >> 3;            // staging row within 8-row group
    const int sk   = (lane & 7) * 8;       // staging k offset (elems)
    const int wr   = (w >> 1) * 64;        // wave row block
    const int wc   = (w & 1) * 64;         // wave col block
    const int lr   = lane & 15;
    const int lk   = (lane >> 4) * 8;      // k offset within 32 (elems)

    f32x4 acc[4][4] = {};

    for (int k0 = 0; k0 < K; k0 += 64) {
        #pragma unroll
        for (int i = 0; i < 4; ++i) {
            const int c = i * 4 + w;                  // 1KB chunk id (wave-uniform)
            const int cr = c * 8 + srow;              // tile row 0..127
            gload16(A  + (size_t)(row0 + cr) * lda + k0 + sk, (char*)As + c * 1024);
            gload16(Bt + (size_t)(col0 + cr) * K   + k0 + sk, (char*)Bs + c * 1024);
        }
        __syncthreads();
        #pragma unroll
        for (int ks = 0; ks < 2; ++ks) {
            s16x8 af[4], bfr[4];
            #pragma unroll
            for (int mi = 0; mi < 4; ++mi)
                af[mi] = *(const s16x8*)&As[(wr + mi * 16 + lr) * 64 + ks * 32 + lk];
            #pragma unroll
            for (int ni = 0; ni < 4; ++ni)
                bfr[ni] = *(const s16x8*)&Bs[(wc + ni * 16 + lr) * 64 + ks * 32 + lk];
            #pragma unroll
            for (int mi = 0; mi < 4; ++mi)
                #pragma unroll
                for (int ni = 0; ni < 4; ++ni)
                    acc[mi][ni] = __builtin_amdgcn_mfma_f32_16x16x32_bf16(
                        af[mi], bfr[ni], acc[mi][ni], 0, 0, 0);
        }
        __syncthreads();
    }

    // epilogue: C/D layout col=lane&15, row=(lane>>4)*4+r  [m89/m91]
    const int crow = (lane >> 4) * 4;
    const int ccol = lane & 15;
    #pragma unroll
    for (int ni = 0; ni < 4; ++ni) {
        const int col = col0 + wc + ni * 16 + ccol;
        const float bc = bias[col];
        #pragma unroll
        for (int mi = 0; mi < 4; ++mi) {
            #pragma unroll
            for (int r = 0; r < 4; ++r) {
                const int row = row0 + wr + mi * 16 + crow + r;
                float v = acc[mi][ni][r] + bc;
                if (ACT == 1) v = gelu_exact(v);
                const size_t idx = (size_t)row * N + col;
                if (res) v += res[idx];
                if (Cf) Cf[idx] = v;
                if (Cb) Cb[idx] = f2b(v);
            }
        }
    }
}

// ---------------------------------------------------------------------------
// Weight transpose+convert: W[K,N] f32 -> Wt[N,K] bf16.
// ---------------------------------------------------------------------------
__global__ __launch_bounds__(256) void wtrans(
    const float* __restrict__ W, ushort_t* __restrict__ Wt, int K, int N)
{
    __shared__ float tile[32][33];
    const int n0 = blockIdx.x * 32, k0 = blockIdx.y * 32;
    const int tx = threadIdx.x & 31, ty = threadIdx.x >> 5;  // ty: 0..7
    #pragma unroll
    for (int j = 0; j < 4; ++j)
        tile[ty + j * 8][tx] = W[(size_t)(k0 + ty + j * 8) * N + n0 + tx];
    __syncthreads();
    #pragma unroll
    for (int j = 0; j < 4; ++j)
        Wt[(size_t)(n0 + ty + j * 8) * K + k0 + tx] = f2b(tile[tx][ty + j * 8]);
}

// x f32 -> bf16 (vectorized), n4 = n/4
__global__ __launch_bounds__(256) void conv_f2b(
    const float* __restrict__ in, ushort_t* __restrict__ out, int n4)
{
    const int i = blockIdx.x * 256 + threadIdx.x;
    if (i >= n4) return;
    float4 v = ((const float4*)in)[i];
    ushort4 o; o.x = f2b(v.x); o.y = f2b(v.y); o.z = f2b(v.z); o.w = f2b(v.w);
    ((ushort4*)out)[i] = o;
}

// concat biases: bqkv[3072] = bq|bk|bv ; bad[768] = a256_b1|a512_b1
__global__ __launch_bounds__(256) void prep_bias(
    const float* bq, const float* bk, const float* bv,
    const float* b1, const float* b2, float* bqkv, float* bad)
{
    const int t = blockIdx.x * 256 + threadIdx.x;
    if (t < 1024) { bqkv[t] = bq[t]; bqkv[1024 + t] = bk[t]; bqkv[2048 + t] = bv[t]; }
    if (t < 256) bad[t] = b1[t];
    if (t < 512) bad[256 + t] = b2[t];
}

// ---------------------------------------------------------------------------
// Per-head LN over DH=64 on strided qkv buffer (token stride 3072), in place.
// ---------------------------------------------------------------------------
__global__ __launch_bounds__(256) void ln_head2(
    float* __restrict__ t, const float* __restrict__ g, const float* __restrict__ b, int off)
{
    const int gw   = (blockIdx.x * 256 + threadIdx.x) >> 6;   // token*16+head
    const int lane = threadIdx.x & 63;
    const int tok = gw >> 4, hh = gw & 15;
    const size_t base = (size_t)tok * 3072 + off + hh * 64 + lane;
    float v = t[base];
    float s = v;
    #pragma unroll
    for (int o = 32; o >= 1; o >>= 1) s += __shfl_xor(s, o);
    const float mean = s * (1.0f / 64.0f);
    const float d = v - mean;
    float s2 = d * d;
    #pragma unroll
    for (int o = 32; o >= 1; o >>= 1) s2 += __shfl_xor(s2, o);
    t[base] = d * rsqrtf(s2 * (1.0f / 64.0f) + 1e-5f) * g[lane] + b[lane];
}

// ---------------------------------------------------------------------------
// Windowed causal attention on strided f32 qkv; bf16 output.
// Wave owns 16 queries; lane = (query qi, d-quarter dg).
// ---------------------------------------------------------------------------
__global__ __launch_bounds__(256) void attn_win3(
    const float* __restrict__ qkv, ushort_t* __restrict__ o)
{
    const int wid  = (blockIdx.x * 256 + threadIdx.x) >> 6;
    const int lane = threadIdx.x & 63;
    const int qi = lane & 15;
    const int dg = lane >> 4;
    const int qt = wid & 127;
    const int hh = (wid >> 7) & 15;
    const int b  = wid >> 11;
    const int i  = qt * 16 + qi;

    const size_t tokstr = 3072;
    const size_t qbase = ((size_t)(b * S_ + i)) * tokstr + hh * 64 + dg * 16;

    float qr[16];
    #pragma unroll
    for (int t = 0; t < 4; ++t)
        *(float4*)&qr[t * 4] = *(const float4*)(qkv + qbase + t * 4);

    float acc[16] = {};
    float M = -1e30f, L = 0.0f;
    const int i0  = qt * 16;
    const int jlo = (i0 - WIN_) > 0 ? (i0 - WIN_) : 0;
    const int jhi = i0 + 15;

    #pragma unroll 2
    for (int j = jlo; j <= jhi; ++j) {
        const size_t kb = ((size_t)(b * S_ + j)) * tokstr + 1024 + hh * 64 + dg * 16;
        float kr[16], vr[16];
        #pragma unroll
        for (int t = 0; t < 4; ++t) {
            *(float4*)&kr[t * 4] = *(const float4*)(qkv + kb + t * 4);
            *(float4*)&vr[t * 4] = *(const float4*)(qkv + kb + 1024 + t * 4);
        }
        float s = 0.0f;
        #pragma unroll
        for (int t = 0; t < 16; ++t) s = fmaf(qr[t], kr[t], s);
        s += __shfl_xor(s, 16);
        s += __shfl_xor(s, 32);
        s *= 0.125f;
        const bool ok = (j <= i) && ((i - j) <= WIN_);
        s = ok ? s : -1e30f;
        const float nM = fmaxf(M, s);
        const float alpha = __expf(M - nM);
        const float e = ok ? __expf(s - nM) : 0.0f;
        L = L * alpha + e;
        #pragma unroll
        for (int t = 0; t < 16; ++t)
            acc[t] = fmaf(acc[t], alpha, e * vr[t]);
        M = nM;
    }

    const float inv = 1.0f / L;
    const size_t obase = ((size_t)(b * S_ + i)) * 1024 + hh * 64 + dg * 16;
    union { ushort_t u[8]; ushort4 q[2]; } pk0, pk1;
    #pragma unroll
    for (int t = 0; t < 8; ++t) pk0.u[t] = f2b(acc[t] * inv);
    #pragma unroll
    for (int t = 0; t < 8; ++t) pk1.u[t] = f2b(acc[8 + t] * inv);
    *(ushort4*)(o + obase)     = pk0.q[0];
    *(ushort4*)(o + obase + 4) = pk0.q[1];
    *(ushort4*)(o + obase + 8)  = pk1.q[0];
    *(ushort4*)(o + obase + 12) = pk1.q[1];
}

// ---------------------------------------------------------------------------
// Token LayerNorm: in (f32 or bf16) -> bf16. One block per token. In-place ok.
// ---------------------------------------------------------------------------
template <int N, typename TI>
__global__ __launch_bounds__(256) void ln_token2(
    const TI* __restrict__ in, ushort_t* __restrict__ outp,
    const float* __restrict__ g, const float* __restrict__ b)
{
    constexpr int NPT = N / 256;
    const int t = blockIdx.x;
    const TI* row = in + (size_t)t * N;
    float vals[NPT];
    float s = 0.0f, s2 = 0.0f;
    #pragma unroll
    for (int i = 0; i < NPT; ++i) {
        float x;
        if (sizeof(TI) == 2) x = b2f(((const ushort_t*)row)[i * 256 + threadIdx.x]);
        else                 x = ((const float*)row)[i * 256 + threadIdx.x];
        vals[i] = x;
        s += x;
        s2 = fmaf(x, x, s2);
    }
    #pragma unroll
    for (int o = 32; o >= 1; o >>= 1) { s += __shfl_xor(s, o); s2 += __shfl_xor(s2, o); }
    __shared__ float rs[4], rq[4];
    const int wid = threadIdx.x >> 6, lane = threadIdx.x & 63;
    if (lane == 0) { rs[wid] = s; rq[wid] = s2; }
    __syncthreads();
    s  = rs[0] + rs[1] + rs[2] + rs[3];
    s2 = rq[0] + rq[1] + rq[2] + rq[3];
    const float mean = s * (1.0f / N);
    const float var  = s2 * (1.0f / N) - mean * mean;
    const float rstd = rsqrtf(var + 1e-5f);
    #pragma unroll
    for (int i = 0; i < NPT; ++i) {
        const int idx = i * 256 + threadIdx.x;
        outp[(size_t)t * N + idx] = f2b((vals[i] - mean) * rstd * g[idx] + b[idx]);
    }
}

// ---------------------------------------------------------------------------
// Final combine: out = h + out*wm + adaptive*(1-wm).
// ---------------------------------------------------------------------------
__global__ __launch_bounds__(256) void combine2(
    float* __restrict__ outp, const float* __restrict__ h,
    const ushort_t* __restrict__ xnb, const float* __restrict__ a0,
    const float* __restrict__ a1, const float* __restrict__ wm,
    const int* __restrict__ widx)
{
    const size_t idx = (size_t)blockIdx.x * 256 + threadIdx.x;
    const int t = (int)(idx >> 10);
    const float w = wm[t];
    const int sel = widx[t];
    const float ad = (sel == 0) ? a0[idx] : ((sel == 1) ? a1[idx] : b2f(xnb[idx]));
    outp[idx] = h[idx] + outp[idx] * w + ad * (1.0f - w);
}

// ---------------------------------------------------------------------------
extern "C" void kernel_launch(void* const* d_in, const int* in_sizes, int n_in,
                              void* d_out, int out_size, void* d_ws, size_t ws_size,
                              hipStream_t stream)
{
    const float* x     = (const float*)d_in[0];
    const float* wm    = (const float*)d_in[1];
    const float* wq    = (const float*)d_in[2];
    const float* bq    = (const float*)d_in[3];
    const float* wk    = (const float*)d_in[4];
    const float* bk    = (const float*)d_in[5];
    const float* wv    = (const float*)d_in[6];
    const float* bv    = (const float*)d_in[7];
    const float* wo    = (const float*)d_in[8];
    const float* bo    = (const float*)d_in[9];
    const float* lnq_g = (const float*)d_in[10];
    const float* lnq_b = (const float*)d_in[11];
    const float* lnk_g = (const float*)d_in[12];
    const float* lnk_b = (const float*)d_in[13];
    const float* fc1_w = (const float*)d_in[14];
    const float* fc1_b = (const float*)d_in[15];
    const float* fc2_w = (const float*)d_in[16];
    const float* fc2_b = (const float*)d_in[17];
    const float* lni_g = (const float*)d_in[18];
    const float* lni_b = (const float*)d_in[19];
    const float* lnh_g = (const float*)d_in[20];
    const float* lnh_b = (const float*)d_in[21];
    const float* a256_w1 = (const float*)d_in[22];
    const float* a256_b1 = (const float*)d_in[23];
    const float* a256_w2 = (const float*)d_in[24];
    const float* a256_b2 = (const float*)d_in[25];
    const float* a512_w1 = (const float*)d_in[26];
    const float* a512_b1 = (const float*)d_in[27];
    const float* a512_w2 = (const float*)d_in[28];
    const float* a512_b2 = (const float*)d_in[29];
    const int*   widx    = (const int*)d_in[30];

    float* out = (float*)d_out;

    // ---- workspace carve-up (bytes, 256-aligned) ----
    char* p = (char*)d_ws;
    auto alloc = [&](size_t bytes) { char* r = p; p += (bytes + 255) & ~(size_t)255; return r; };
    float*    qkv   = (float*)   alloc((size_t)MTOK * 3072 * 4);  // 48MB (a0/a1 alias later)
    float*    hb    = (float*)   alloc((size_t)MTOK * 1024 * 4);  // 16.8MB
    ushort_t* xnb   = (ushort_t*)alloc((size_t)MTOK * 1024 * 2);  // 8MB
    ushort_t* hidb  = (ushort_t*)alloc((size_t)MTOK * 4096 * 2);  // 32MB (xb, attnb alias)
    ushort_t* tA    = (ushort_t*)alloc((size_t)MTOK * 768 * 2);   // 6MB
    ushort_t* WqkvT = (ushort_t*)alloc((size_t)3072 * 1024 * 2);
    ushort_t* WoT   = (ushort_t*)alloc((size_t)1024 * 1024 * 2);
    ushort_t* fc1T  = (ushort_t*)alloc((size_t)4096 * 1024 * 2);
    ushort_t* fc2T  = (ushort_t*)alloc((size_t)1024 * 4096 * 2);
    ushort_t* Wad1T = (ushort_t*)alloc((size_t)768 * 1024 * 2);
    ushort_t* w2aT  = (ushort_t*)alloc((size_t)1024 * 256 * 2);
    ushort_t* w2bT  = (ushort_t*)alloc((size_t)1024 * 512 * 2);
    float*    bqkv  = (float*)   alloc(3072 * 4);
    float*    bad   = (float*)   alloc(768 * 4);
    // aliases (lifetimes: xb dead after qkv GEMM; attnb dead after wo GEMM;
    // both precede fc1's write of hidb. qkv dead after attn; a0/a1 written later.)
    ushort_t* xb    = hidb;
    ushort_t* attnb = hidb + (size_t)MTOK * 1024;  // 8MB in
    float*    a0    = qkv;
    float*    a1    = qkv + (size_t)MTOK * 1024;

    const dim3 blk(256);

    // ---- prep: biases, x->bf16, weight transposes ----
    prep_bias<<<4, blk, 0, stream>>>(bq, bk, bv, a256_b1, a512_b1, bqkv, bad);
    conv_f2b<<<(MTOK * 1024 / 4 + 255) / 256, blk, 0, stream>>>(x, xb, MTOK * 1024 / 4);
    wtrans<<<dim3(32, 32),  blk, 0, stream>>>(wq, WqkvT,                 1024, 1024);
    wtrans<<<dim3(32, 32),  blk, 0, stream>>>(wk, WqkvT + 1024 * 1024,   1024, 1024);
    wtrans<<<dim3(32, 32),  blk, 0, stream>>>(wv, WqkvT + 2048 * 1024,   1024, 1024);
    wtrans<<<dim3(32, 32),  blk, 0, stream>>>(wo, WoT,                   1024, 1024);
    wtrans<<<dim3(128, 32), blk, 0, stream>>>(fc1_w, fc1T,               1024, 4096);
    wtrans<<<dim3(32, 128), blk, 0, stream>>>(fc2_w, fc2T,               4096, 1024);
    wtrans<<<dim3(8, 32),   blk, 0, stream>>>(a256_w1, Wad1T,            1024, 256);
    wtrans<<<dim3(16, 32),  blk, 0, stream>>>(a512_w1, Wad1T + 256 * 1024, 1024, 512);
    wtrans<<<dim3(32, 8),   blk, 0, stream>>>(a256_w2, w2aT,             256, 1024);
    wtrans<<<dim3(32, 16),  blk, 0, stream>>>(a512_w2, w2bT,             512, 1024);

    // ---- fused QKV projection: [4096,1024] @ [1024,3072] -> f32 qkv ----
    gemm_mfma<0><<<dim3(24, 32), blk, 0, stream>>>(xb, 1024, WqkvT, bqkv, nullptr,
                                                   qkv, nullptr, MTOK, 3072, 1024);
    ln_head2<<<MTOK * NH_ / 4, blk, 0, stream>>>(qkv, lnq_g, lnq_b, 0);
    ln_head2<<<MTOK * NH_ / 4, blk, 0, stream>>>(qkv, lnk_g, lnk_b, 1024);
    attn_win3<<<B_ * NH_ * (S_ / 16) / 4, blk, 0, stream>>>(qkv, attnb);

    // ---- output projection + residual -> h (f32) ----
    gemm_mfma<0><<<dim3(8, 32), blk, 0, stream>>>(attnb, 1024, WoT, bo, x,
                                                  hb, nullptr, MTOK, 1024, 1024);
    ln_token2<DM_, float><<<MTOK, blk, 0, stream>>>(hb, xnb, lni_g, lni_b);

    // ---- base FFN ----
    gemm_mfma<1><<<dim3(32, 32), blk, 0, stream>>>(xnb, 1024, fc1T, fc1_b, nullptr,
                                                   nullptr, hidb, MTOK, 4096, 1024);
    ln_token2<DFF_, ushort_t><<<MTOK, blk, 0, stream>>>(hidb, hidb, lnh_g, lnh_b);
    gemm_mfma<0><<<dim3(8, 32), blk, 0, stream>>>(hidb, 4096, fc2T, fc2_b, nullptr,
                                                  out, nullptr, MTOK, 1024, 4096);

    // ---- adapters: fused in-proj (N=768), two out-projs ----
    gemm_mfma<1><<<dim3(6, 32), blk, 0, stream>>>(xnb, 1024, Wad1T, bad, nullptr,
                                                  nullptr, tA, MTOK, 768, 1024);
    gemm_mfma<0><<<dim3(8, 32), blk, 0, stream>>>(tA, 768, w2aT, a256_b2, nullptr,
                                                  a0, nullptr, MTOK, 1024, 256);
    gemm_mfma<0><<<dim3(8, 32), blk, 0, stream>>>(tA + 256, 768, w2bT, a512_b2, nullptr,
                                                  a1, nullptr, MTOK, 1024, 512);

    // ---- final routed combine ----
    combine2<<<(int)((size_t)MTOK * 1024 / 256), blk, 0, stream>>>(
        out, hb, xnb, a0, a1, wm, widx);
}

// Round 4
// 636.506 us; speedup vs baseline: 4.4060x; 1.0220x over previous
//
#include <hip/hip_runtime.h>
#include <math.h>

#define B_   2
#define S_   2048
#define DM_  1024
#define NH_  16
#define DH_  64
#define DFF_ 4096
#define WIN_ 256
#define MTOK (B_*S_)   // 4096 tokens

typedef unsigned short ushort_t;
typedef short s16x8 __attribute__((ext_vector_type(8)));
typedef float f32x4 __attribute__((ext_vector_type(4)));

__device__ __forceinline__ float b2f(ushort_t u) {
    union { unsigned int i; float f; } c; c.i = ((unsigned int)u) << 16; return c.f;
}
__device__ __forceinline__ ushort_t f2b(float f) {
    union { float f; unsigned int i; } c; c.f = f;
    unsigned int r = c.i + 0x7fffu + ((c.i >> 16) & 1u);   // RNE
    return (ushort_t)(r >> 16);
}
__device__ __forceinline__ float gelu_exact(float x) {
    return 0.5f * x * (1.0f + erff(x * 0.70710678118654752f));
}
__device__ __forceinline__ void gload16(const void* g, void* l) {
    __builtin_amdgcn_global_load_lds(
        (const __attribute__((address_space(1))) unsigned int*)g,
        (__attribute__((address_space(3))) unsigned int*)l, 16, 0, 0);
}

// ---------------------------------------------------------------------------
// bf16 MFMA GEMM core (m97 structure): 128x128 tile, BK=64, 4 waves,
// 16x16x32 MFMA, global_load_lds staging. Bt is [N x ldb] (row = out col).
// ACT: 0=bias(+res), 1=gelu(bias)(+res), 2=raw partial (no bias/act/res).
// ---------------------------------------------------------------------------
template <int ACT>
__device__ __forceinline__ void gemm_core(
    const ushort_t* __restrict__ A, int lda,
    const ushort_t* __restrict__ Bt, int ldb,
    const float* __restrict__ bias, const float* __restrict__ res,
    float* __restrict__ Cf, ushort_t* __restrict__ Cb,
    int N, int Kc, int bx, int by)
{
    __shared__ __align__(16) ushort_t As[128 * 64];
    __shared__ __align__(16) ushort_t Bs[128 * 64];

    const int tid  = threadIdx.x;
    const int lane = tid & 63;
    const int w    = tid >> 6;
    const int row0 = by * 128;
    const int col0 = bx * 128;

    const int srow = lane >> 3;
    const int sk   = (lane & 7) * 8;
    const int wr   = (w >> 1) * 64;
    const int wc   = (w & 1) * 64;
    const int lr   = lane & 15;
    const int lk   = (lane >> 4) * 8;

    f32x4 acc[4][4] = {};

    for (int k0 = 0; k0 < Kc; k0 += 64) {
        #pragma unroll
        for (int i = 0; i < 4; ++i) {
            const int c = i * 4 + w;
            const int cr = c * 8 + srow;
            gload16(A  + (size_t)(row0 + cr) * lda + k0 + sk, (char*)As + c * 1024);
            gload16(Bt + (size_t)(col0 + cr) * ldb + k0 + sk, (char*)Bs + c * 1024);
        }
        __syncthreads();
        #pragma unroll
        for (int ks = 0; ks < 2; ++ks) {
            s16x8 af[4], bfr[4];
            #pragma unroll
            for (int mi = 0; mi < 4; ++mi)
                af[mi] = *(const s16x8*)&As[(wr + mi * 16 + lr) * 64 + ks * 32 + lk];
            #pragma unroll
            for (int ni = 0; ni < 4; ++ni)
                bfr[ni] = *(const s16x8*)&Bs[(wc + ni * 16 + lr) * 64 + ks * 32 + lk];
            #pragma unroll
            for (int mi = 0; mi < 4; ++mi)
                #pragma unroll
                for (int ni = 0; ni < 4; ++ni)
                    acc[mi][ni] = __builtin_amdgcn_mfma_f32_16x16x32_bf16(
                        af[mi], bfr[ni], acc[mi][ni], 0, 0, 0);
        }
        __syncthreads();
    }

    const int crow = (lane >> 4) * 4;
    const int ccol = lane & 15;
    #pragma unroll
    for (int ni = 0; ni < 4; ++ni) {
        const int col = col0 + wc + ni * 16 + ccol;
        const float bc = (ACT == 2) ? 0.0f : bias[col];
        #pragma unroll
        for (int mi = 0; mi < 4; ++mi) {
            #pragma unroll
            for (int r = 0; r < 4; ++r) {
                const int row = row0 + wr + mi * 16 + crow + r;
                float v = acc[mi][ni][r] + bc;
                if (ACT == 1) v = gelu_exact(v);
                const size_t idx = (size_t)row * N + col;
                if (ACT != 2 && res) v += res[idx];
                if (Cf) Cf[idx] = v;
                if (ACT != 2 && Cb) Cb[idx] = f2b(v);
            }
        }
    }
}

template <int ACT>
__global__ __launch_bounds__(256) void gemm_mfma(
    const ushort_t* __restrict__ A, int lda,
    const ushort_t* __restrict__ Bt,
    const float* __restrict__ bias, const float* __restrict__ res,
    float* __restrict__ Cf, ushort_t* __restrict__ Cb,
    int M, int N, int K)
{
    gemm_core<ACT>(A, lda, Bt, K, bias, res, Cf, Cb, N, K, blockIdx.x, blockIdx.y);
}

// fc2 with split-K=2: z=0 -> p0 (d_out), z=1 -> p1. Raw partials, no bias.
__global__ __launch_bounds__(256) void gemm_fc2_sk(
    const ushort_t* __restrict__ A, const ushort_t* __restrict__ Bt,
    float* __restrict__ p0, float* __restrict__ p1)
{
    const int z = blockIdx.z;
    gemm_core<2>(A + z * 2048, 4096, Bt + z * 2048, 4096, nullptr, nullptr,
                 z ? p1 : p0, nullptr, 1024, 2048, blockIdx.x, blockIdx.y);
}

// both adapter out-projections in one dispatch (z selects parameter set)
__global__ __launch_bounds__(256) void gemm_adapters(
    const ushort_t* __restrict__ tA, const ushort_t* __restrict__ w2a,
    const ushort_t* __restrict__ w2b, const float* __restrict__ b2a,
    const float* __restrict__ b2b, float* __restrict__ a0, float* __restrict__ a1)
{
    const int z = blockIdx.z;
    const ushort_t* Ap = z ? tA + 256 : tA;
    const ushort_t* Wp = z ? w2b : w2a;
    const float*    bp = z ? b2b : b2a;
    float*          Cp = z ? a1 : a0;
    const int ldbz = z ? 512 : 256;
    gemm_core<0>(Ap, 768, Wp, ldbz, bp, nullptr, Cp, nullptr, 1024, ldbz,
                 blockIdx.x, blockIdx.y);
}

// ---------------------------------------------------------------------------
// Weight transpose+convert: W[K,N] f32 -> Wt[N,K] bf16.
// ---------------------------------------------------------------------------
__device__ __forceinline__ void wtrans_core(
    const float* __restrict__ W, ushort_t* __restrict__ Wt, int K, int N,
    int bx, int by)
{
    __shared__ float tile[32][33];
    const int n0 = bx * 32, k0 = by * 32;
    const int tx = threadIdx.x & 31, ty = threadIdx.x >> 5;
    #pragma unroll
    for (int j = 0; j < 4; ++j)
        tile[ty + j * 8][tx] = W[(size_t)(k0 + ty + j * 8) * N + n0 + tx];
    __syncthreads();
    #pragma unroll
    for (int j = 0; j < 4; ++j)
        Wt[(size_t)(n0 + ty + j * 8) * K + k0 + tx] = f2b(tile[tx][ty + j * 8]);
}

__global__ __launch_bounds__(256) void wtrans(
    const float* __restrict__ W, ushort_t* __restrict__ Wt, int K, int N)
{
    wtrans_core(W, Wt, K, N, blockIdx.x, blockIdx.y);
}

// the four 1024x1024 weights in one dispatch
__global__ __launch_bounds__(256) void wtrans4(
    const float* w0, const float* w1, const float* w2, const float* w3,
    ushort_t* d0, ushort_t* d1, ushort_t* d2, ushort_t* d3)
{
    const int z = blockIdx.z;
    const float* W = (z == 0) ? w0 : (z == 1) ? w1 : (z == 2) ? w2 : w3;
    ushort_t* Wt   = (z == 0) ? d0 : (z == 1) ? d1 : (z == 2) ? d2 : d3;
    wtrans_core(W, Wt, 1024, 1024, blockIdx.x, blockIdx.y);
}

__global__ __launch_bounds__(256) void conv_f2b(
    const float* __restrict__ in, ushort_t* __restrict__ out, int n4)
{
    const int i = blockIdx.x * 256 + threadIdx.x;
    if (i >= n4) return;
    float4 v = ((const float4*)in)[i];
    ushort4 o; o.x = f2b(v.x); o.y = f2b(v.y); o.z = f2b(v.z); o.w = f2b(v.w);
    ((ushort4*)out)[i] = o;
}

__global__ __launch_bounds__(256) void prep_bias(
    const float* bq, const float* bk, const float* bv,
    const float* b1, const float* b2, float* bqkv, float* bad)
{
    const int t = blockIdx.x * 256 + threadIdx.x;
    if (t < 1024) { bqkv[t] = bq[t]; bqkv[1024 + t] = bk[t]; bqkv[2048 + t] = bv[t]; }
    if (t < 256) bad[t] = b1[t];
    if (t < 512) bad[256 + t] = b2[t];
}

// ---------------------------------------------------------------------------
// Per-head LN over DH=64 on strided qkv (token stride 3072); q and k in one
// dispatch (gw2&1 selects which). In place.
// ---------------------------------------------------------------------------
__global__ __launch_bounds__(256) void ln_head3(
    float* __restrict__ t, const float* __restrict__ qg, const float* __restrict__ qb,
    const float* __restrict__ kg, const float* __restrict__ kb)
{
    const int gw2  = (blockIdx.x * 256 + threadIdx.x) >> 6;
    const int lane = threadIdx.x & 63;
    const int sel = gw2 & 1;
    const int gw  = gw2 >> 1;                 // token*16 + head
    const int tok = gw >> 4, hh = gw & 15;
    const size_t base = (size_t)tok * 3072 + sel * 1024 + hh * 64 + lane;
    const float* g = sel ? kg : qg;
    const float* b = sel ? kb : qb;
    float v = t[base];
    float s = v;
    #pragma unroll
    for (int o = 32; o >= 1; o >>= 1) s += __shfl_xor(s, o);
    const float mean = s * (1.0f / 64.0f);
    const float d = v - mean;
    float s2 = d * d;
    #pragma unroll
    for (int o = 32; o >= 1; o >>= 1) s2 += __shfl_xor(s2, o);
    t[base] = d * rsqrtf(s2 * (1.0f / 64.0f) + 1e-5f) * g[lane] + b[lane];
}

// ---------------------------------------------------------------------------
// Windowed causal attention v4: block = (b, h, 32-query tile), 4 waves.
// wave = (qhalf, khalf): 16 queries x half the key window; partial online
// softmax per wave, flash-merge across khalf pairs via LDS.
// lane = (qi = lane&15, dg = lane>>4).
// ---------------------------------------------------------------------------
__global__ __launch_bounds__(256) void attn_win4(
    const float* __restrict__ qkv, ushort_t* __restrict__ o)
{
    __shared__ float sM[2][64], sL[2][64];
    __shared__ float4 sA[2][64][4];

    const int bid  = blockIdx.x;
    const int qt32 = bid & 63;
    const int hh   = (bid >> 6) & 15;
    const int b    = bid >> 10;
    const int w     = threadIdx.x >> 6;
    const int lane  = threadIdx.x & 63;
    const int qhalf = w & 1;
    const int khalf = w >> 1;
    const int qi = lane & 15;
    const int dg = lane >> 4;

    const int i0 = qt32 * 32 + qhalf * 16;
    const int i  = i0 + qi;

    const size_t tokstr = 3072;
    const size_t qbase = ((size_t)(b * S_ + i)) * tokstr + hh * 64 + dg * 16;

    float qr[16];
    #pragma unroll
    for (int t = 0; t < 4; ++t)
        *(float4*)&qr[t * 4] = *(const float4*)(qkv + qbase + t * 4);

    float acc[16] = {};
    float M = -1e30f, L = 0.0f;

    const int jlo = (i0 - WIN_) > 0 ? (i0 - WIN_) : 0;
    const int jhi = i0 + 15;
    const int mid = (jlo + jhi + 1) >> 1;
    const int kb  = khalf ? mid : jlo;
    const int ke  = khalf ? jhi : mid - 1;

    #pragma unroll 2
    for (int j = kb; j <= ke; ++j) {
        const size_t kvb = ((size_t)(b * S_ + j)) * tokstr + 1024 + hh * 64 + dg * 16;
        float kr[16], vr[16];
        #pragma unroll
        for (int t = 0; t < 4; ++t) {
            *(float4*)&kr[t * 4] = *(const float4*)(qkv + kvb + t * 4);
            *(float4*)&vr[t * 4] = *(const float4*)(qkv + kvb + 1024 + t * 4);
        }
        float s = 0.0f;
        #pragma unroll
        for (int t = 0; t < 16; ++t) s = fmaf(qr[t], kr[t], s);
        s += __shfl_xor(s, 16);
        s += __shfl_xor(s, 32);
        s *= 0.125f;
        const bool ok = (j <= i) && ((i - j) <= WIN_);
        s = ok ? s : -1e30f;
        const float nM = fmaxf(M, s);
        const float alpha = __expf(M - nM);
        const float e = ok ? __expf(s - nM) : 0.0f;
        L = L * alpha + e;
        #pragma unroll
        for (int t = 0; t < 16; ++t)
            acc[t] = fmaf(acc[t], alpha, e * vr[t]);
        M = nM;
    }

    // flash-merge: khalf==1 publishes partials, khalf==0 merges + writes.
    if (khalf == 1) {
        sM[qhalf][lane] = M;
        sL[qhalf][lane] = L;
        #pragma unroll
        for (int t = 0; t < 4; ++t)
            sA[qhalf][lane][t] = *(const float4*)&acc[t * 4];
    }
    __syncthreads();
    if (khalf == 0) {
        const float oM = sM[qhalf][lane];
        const float oL = sL[qhalf][lane];
        const float nM = fmaxf(M, oM);
        const float c0 = __expf(M - nM);
        const float c1 = __expf(oM - nM);
        const float Lt = L * c0 + oL * c1;
        float oA[16];
        #pragma unroll
        for (int t = 0; t < 4; ++t)
            *(float4*)&oA[t * 4] = sA[qhalf][lane][t];
        const float inv = 1.0f / Lt;
        const size_t obase = ((size_t)(b * S_ + i)) * 1024 + hh * 64 + dg * 16;
        ushort4 pk[4];
        #pragma unroll
        for (int t = 0; t < 16; ++t) {
            const float vv = (acc[t] * c0 + oA[t] * c1) * inv;
            ((ushort_t*)pk)[t] = f2b(vv);
        }
        #pragma unroll
        for (int t = 0; t < 4; ++t)
            *(ushort4*)(o + obase + t * 4) = pk[t];
    }
}

// ---------------------------------------------------------------------------
// Token LayerNorm: in (f32 or bf16) -> bf16. One block per token.
// ---------------------------------------------------------------------------
template <int N, typename TI>
__global__ __launch_bounds__(256) void ln_token2(
    const TI* __restrict__ in, ushort_t* __restrict__ outp,
    const float* __restrict__ g, const float* __restrict__ b)
{
    constexpr int NPT = N / 256;
    const int t = blockIdx.x;
    const TI* row = in + (size_t)t * N;
    float vals[NPT];
    float s = 0.0f, s2 = 0.0f;
    #pragma unroll
    for (int i = 0; i < NPT; ++i) {
        float x;
        if (sizeof(TI) == 2) x = b2f(((const ushort_t*)row)[i * 256 + threadIdx.x]);
        else                 x = ((const float*)row)[i * 256 + threadIdx.x];
        vals[i] = x;
        s += x;
        s2 = fmaf(x, x, s2);
    }
    #pragma unroll
    for (int o = 32; o >= 1; o >>= 1) { s += __shfl_xor(s, o); s2 += __shfl_xor(s2, o); }
    __shared__ float rs[4], rq[4];
    const int wid = threadIdx.x >> 6, lane = threadIdx.x & 63;
    if (lane == 0) { rs[wid] = s; rq[wid] = s2; }
    __syncthreads();
    s  = rs[0] + rs[1] + rs[2] + rs[3];
    s2 = rq[0] + rq[1] + rq[2] + rq[3];
    const float mean = s * (1.0f / N);
    const float var  = s2 * (1.0f / N) - mean * mean;
    const float rstd = rsqrtf(var + 1e-5f);
    #pragma unroll
    for (int i = 0; i < NPT; ++i) {
        const int idx = i * 256 + threadIdx.x;
        outp[(size_t)t * N + idx] = f2b((vals[i] - mean) * rstd * g[idx] + b[idx]);
    }
}

// ---------------------------------------------------------------------------
// Final combine: out = h + (p0+p1+fc2_b)*wm + adaptive*(1-wm).
// ---------------------------------------------------------------------------
__global__ __launch_bounds__(256) void combine3(
    float* __restrict__ outp, const float* __restrict__ p1,
    const float* __restrict__ fc2b, const float* __restrict__ h,
    const ushort_t* __restrict__ xnb, const float* __restrict__ a0,
    const float* __restrict__ a1, const float* __restrict__ wm,
    const int* __restrict__ widx)
{
    const size_t idx = (size_t)blockIdx.x * 256 + threadIdx.x;
    const int t   = (int)(idx >> 10);
    const int col = (int)(idx & 1023);
    const float w = wm[t];
    const int sel = widx[t];
    const float base = outp[idx] + p1[idx] + fc2b[col];
    const float ad = (sel == 0) ? a0[idx] : ((sel == 1) ? a1[idx] : b2f(xnb[idx]));
    outp[idx] = h[idx] + base * w + ad * (1.0f - w);
}

// ---------------------------------------------------------------------------
extern "C" void kernel_launch(void* const* d_in, const int* in_sizes, int n_in,
                              void* d_out, int out_size, void* d_ws, size_t ws_size,
                              hipStream_t stream)
{
    const float* x     = (const float*)d_in[0];
    const float* wm    = (const float*)d_in[1];
    const float* wq    = (const float*)d_in[2];
    const float* bq    = (const float*)d_in[3];
    const float* wk    = (const float*)d_in[4];
    const float* bk    = (const float*)d_in[5];
    const float* wv    = (const float*)d_in[6];
    const float* bv    = (const float*)d_in[7];
    const float* wo    = (const float*)d_in[8];
    const float* bo    = (const float*)d_in[9];
    const float* lnq_g = (const float*)d_in[10];
    const float* lnq_b = (const float*)d_in[11];
    const float* lnk_g = (const float*)d_in[12];
    const float* lnk_b = (const float*)d_in[13];
    const float* fc1_w = (const float*)d_in[14];
    const float* fc1_b = (const float*)d_in[15];
    const float* fc2_w = (const float*)d_in[16];
    const float* fc2_b = (const float*)d_in[17];
    const float* lni_g = (const float*)d_in[18];
    const float* lni_b = (const float*)d_in[19];
    const float* lnh_g = (const float*)d_in[20];
    const float* lnh_b = (const float*)d_in[21];
    const float* a256_w1 = (const float*)d_in[22];
    const float* a256_b1 = (const float*)d_in[23];
    const float* a256_w2 = (const float*)d_in[24];
    const float* a256_b2 = (const float*)d_in[25];
    const float* a512_w1 = (const float*)d_in[26];
    const float* a512_b1 = (const float*)d_in[27];
    const float* a512_w2 = (const float*)d_in[28];
    const float* a512_b2 = (const float*)d_in[29];
    const int*   widx    = (const int*)d_in[30];

    float* out = (float*)d_out;

    char* p = (char*)d_ws;
    auto alloc = [&](size_t bytes) { char* r = p; p += (bytes + 255) & ~(size_t)255; return r; };
    float*    qkv   = (float*)   alloc((size_t)MTOK * 3072 * 4);  // a0/a1 alias later
    float*    hb    = (float*)   alloc((size_t)MTOK * 1024 * 4);
    ushort_t* xnb   = (ushort_t*)alloc((size_t)MTOK * 1024 * 2);
    ushort_t* hidb  = (ushort_t*)alloc((size_t)MTOK * 4096 * 2);  // xb, attnb alias
    ushort_t* tA    = (ushort_t*)alloc((size_t)MTOK * 768 * 2);
    ushort_t* WqkvT = (ushort_t*)alloc((size_t)3072 * 1024 * 2);
    ushort_t* WoT   = (ushort_t*)alloc((size_t)1024 * 1024 * 2);
    ushort_t* fc1T  = (ushort_t*)alloc((size_t)4096 * 1024 * 2);
    ushort_t* fc2T  = (ushort_t*)alloc((size_t)1024 * 4096 * 2);
    ushort_t* Wad1T = (ushort_t*)alloc((size_t)768 * 1024 * 2);
    ushort_t* w2aT  = (ushort_t*)alloc((size_t)1024 * 256 * 2);
    ushort_t* w2bT  = (ushort_t*)alloc((size_t)1024 * 512 * 2);
    float*    bqkv  = (float*)   alloc(3072 * 4);
    float*    bad   = (float*)   alloc(768 * 4);
    float*    p1    = (float*)   alloc((size_t)MTOK * 1024 * 4);  // fc2 split-K partial
    // aliases: xb dead after qkv GEMM; attnb dead after wo GEMM; both precede
    // fc1's write of hidb. qkv dead after attn; a0/a1 written after fc2.
    ushort_t* xb    = hidb;
    ushort_t* attnb = hidb + (size_t)MTOK * 1024;
    float*    a0    = qkv;
    float*    a1    = qkv + (size_t)MTOK * 1024;

    const dim3 blk(256);

    // ---- prep ----
    prep_bias<<<4, blk, 0, stream>>>(bq, bk, bv, a256_b1, a512_b1, bqkv, bad);
    conv_f2b<<<(MTOK * 1024 / 4 + 255) / 256, blk, 0, stream>>>(x, xb, MTOK * 1024 / 4);
    wtrans4<<<dim3(32, 32, 4), blk, 0, stream>>>(wq, wk, wv, wo,
        WqkvT, WqkvT + 1024 * 1024, WqkvT + 2048 * 1024, WoT);
    wtrans<<<dim3(128, 32), blk, 0, stream>>>(fc1_w, fc1T, 1024, 4096);
    wtrans<<<dim3(32, 128), blk, 0, stream>>>(fc2_w, fc2T, 4096, 1024);
    wtrans<<<dim3(8, 32),   blk, 0, stream>>>(a256_w1, Wad1T, 1024, 256);
    wtrans<<<dim3(16, 32),  blk, 0, stream>>>(a512_w1, Wad1T + 256 * 1024, 1024, 512);
    wtrans<<<dim3(32, 8),   blk, 0, stream>>>(a256_w2, w2aT, 256, 1024);
    wtrans<<<dim3(32, 16),  blk, 0, stream>>>(a512_w2, w2bT, 512, 1024);

    // ---- QKV projection + per-head LN + attention ----
    gemm_mfma<0><<<dim3(24, 32), blk, 0, stream>>>(xb, 1024, WqkvT, bqkv, nullptr,
                                                   qkv, nullptr, MTOK, 3072, 1024);
    ln_head3<<<MTOK * NH_ * 2 / 4, blk, 0, stream>>>(qkv, lnq_g, lnq_b, lnk_g, lnk_b);
    attn_win4<<<B_ * NH_ * (S_ / 32), blk, 0, stream>>>(qkv, attnb);

    // ---- output projection + residual -> h (f32) ----
    gemm_mfma<0><<<dim3(8, 32), blk, 0, stream>>>(attnb, 1024, WoT, bo, x,
                                                  hb, nullptr, MTOK, 1024, 1024);
    ln_token2<DM_, float><<<MTOK, blk, 0, stream>>>(hb, xnb, lni_g, lni_b);

    // ---- base FFN ----
    gemm_mfma<1><<<dim3(32, 32), blk, 0, stream>>>(xnb, 1024, fc1T, fc1_b, nullptr,
                                                   nullptr, hidb, MTOK, 4096, 1024);
    ln_token2<DFF_, ushort_t><<<MTOK, blk, 0, stream>>>(hidb, hidb, lnh_g, lnh_b);
    gemm_fc2_sk<<<dim3(8, 32, 2), blk, 0, stream>>>(hidb, fc2T, out, p1);

    // ---- adapters ----
    gemm_mfma<1><<<dim3(6, 32), blk, 0, stream>>>(xnb, 1024, Wad1T, bad, nullptr,
                                                  nullptr, tA, MTOK, 768, 1024);
    gemm_adapters<<<dim3(8, 32, 2), blk, 0, stream>>>(tA, w2aT, w2bT,
                                                      a256_b2, a512_b2, a0, a1);

    // ---- final routed combine ----
    combine3<<<(int)((size_t)MTOK * 1024 / 256), blk, 0, stream>>>(
        out, p1, fc2_b, hb, xnb, a0, a1, wm, widx);
}

// Round 6
// 382.049 us; speedup vs baseline: 7.3406x; 1.6660x over previous
//
#include <hip/hip_runtime.h>
#include <math.h>

#define B_   2
#define S_   2048
#define DM_  1024
#define NH_  16
#define DH_  64
#define DFF_ 4096
#define WIN_ 256
#define MTOK (B_*S_)   // 4096 tokens

typedef unsigned short ushort_t;
typedef short s16x8 __attribute__((ext_vector_type(8)));
typedef float f32x4 __attribute__((ext_vector_type(4)));

__device__ __forceinline__ float b2f(ushort_t u) {
    union { unsigned int i; float f; } c; c.i = ((unsigned int)u) << 16; return c.f;
}
__device__ __forceinline__ ushort_t f2b(float f) {
    union { float f; unsigned int i; } c; c.f = f;
    unsigned int r = c.i + 0x7fffu + ((c.i >> 16) & 1u);   // RNE
    return (ushort_t)(r >> 16);
}
__device__ __forceinline__ float gelu_exact(float x) {
    return 0.5f * x * (1.0f + erff(x * 0.70710678118654752f));
}
__device__ __forceinline__ void gload16(const void* g, void* l) {
    __builtin_amdgcn_global_load_lds(
        (const __attribute__((address_space(1))) unsigned int*)g,
        (__attribute__((address_space(3))) unsigned int*)l, 16, 0, 0);
}

// ---------------------------------------------------------------------------
// bf16 MFMA GEMM core (m97 structure): 128x128 tile, BK=64, 4 waves.
// ACT: 0=bias(+res), 1=gelu(bias)(+res), 2=raw partial.
// ---------------------------------------------------------------------------
template <int ACT>
__device__ __forceinline__ void gemm_core(
    const ushort_t* __restrict__ A, int lda,
    const ushort_t* __restrict__ Bt, int ldb,
    const float* __restrict__ bias, const float* __restrict__ res,
    float* __restrict__ Cf, ushort_t* __restrict__ Cb,
    int N, int Kc, int bx, int by)
{
    __shared__ __align__(16) ushort_t As[128 * 64];
    __shared__ __align__(16) ushort_t Bs[128 * 64];

    const int tid  = threadIdx.x;
    const int lane = tid & 63;
    const int w    = tid >> 6;
    const int row0 = by * 128;
    const int col0 = bx * 128;

    const int srow = lane >> 3;
    const int sk   = (lane & 7) * 8;
    const int wr   = (w >> 1) * 64;
    const int wc   = (w & 1) * 64;
    const int lr   = lane & 15;
    const int lk   = (lane >> 4) * 8;

    f32x4 acc[4][4] = {};

    for (int k0 = 0; k0 < Kc; k0 += 64) {
        #pragma unroll
        for (int i = 0; i < 4; ++i) {
            const int c = i * 4 + w;
            const int cr = c * 8 + srow;
            gload16(A  + (size_t)(row0 + cr) * lda + k0 + sk, (char*)As + c * 1024);
            gload16(Bt + (size_t)(col0 + cr) * ldb + k0 + sk, (char*)Bs + c * 1024);
        }
        __syncthreads();
        #pragma unroll
        for (int ks = 0; ks < 2; ++ks) {
            s16x8 af[4], bfr[4];
            #pragma unroll
            for (int mi = 0; mi < 4; ++mi)
                af[mi] = *(const s16x8*)&As[(wr + mi * 16 + lr) * 64 + ks * 32 + lk];
            #pragma unroll
            for (int ni = 0; ni < 4; ++ni)
                bfr[ni] = *(const s16x8*)&Bs[(wc + ni * 16 + lr) * 64 + ks * 32 + lk];
            #pragma unroll
            for (int mi = 0; mi < 4; ++mi)
                #pragma unroll
                for (int ni = 0; ni < 4; ++ni)
                    acc[mi][ni] = __builtin_amdgcn_mfma_f32_16x16x32_bf16(
                        af[mi], bfr[ni], acc[mi][ni], 0, 0, 0);
        }
        __syncthreads();
    }

    const int crow = (lane >> 4) * 4;
    const int ccol = lane & 15;
    #pragma unroll
    for (int ni = 0; ni < 4; ++ni) {
        const int col = col0 + wc + ni * 16 + ccol;
        const float bc = (ACT == 2) ? 0.0f : bias[col];
        #pragma unroll
        for (int mi = 0; mi < 4; ++mi) {
            #pragma unroll
            for (int r = 0; r < 4; ++r) {
                const int row = row0 + wr + mi * 16 + crow + r;
                float v = acc[mi][ni][r] + bc;
                if (ACT == 1) v = gelu_exact(v);
                const size_t idx = (size_t)row * N + col;
                if (ACT != 2 && res) v += res[idx];
                if (Cf) Cf[idx] = v;
                if (ACT != 2 && Cb) Cb[idx] = f2b(v);
            }
        }
    }
}

template <int ACT>
__global__ __launch_bounds__(256) void gemm_mfma(
    const ushort_t* __restrict__ A, int lda,
    const ushort_t* __restrict__ Bt,
    const float* __restrict__ bias, const float* __restrict__ res,
    float* __restrict__ Cf, ushort_t* __restrict__ Cb,
    int M, int N, int K)
{
    gemm_core<ACT>(A, lda, Bt, K, bias, res, Cf, Cb, N, K, blockIdx.x, blockIdx.y);
}

__global__ __launch_bounds__(256) void gemm_fc2_sk(
    const ushort_t* __restrict__ A, const ushort_t* __restrict__ Bt,
    float* __restrict__ p0, float* __restrict__ p1)
{
    const int z = blockIdx.z;
    gemm_core<2>(A + z * 2048, 4096, Bt + z * 2048, 4096, nullptr, nullptr,
                 z ? p1 : p0, nullptr, 1024, 2048, blockIdx.x, blockIdx.y);
}

__global__ __launch_bounds__(256) void gemm_adapters(
    const ushort_t* __restrict__ tA, const ushort_t* __restrict__ w2a,
    const ushort_t* __restrict__ w2b, const float* __restrict__ b2a,
    const float* __restrict__ b2b, float* __restrict__ a0, float* __restrict__ a1)
{
    const int z = blockIdx.z;
    const ushort_t* Ap = z ? tA + 256 : tA;
    const ushort_t* Wp = z ? w2b : w2a;
    const float*    bp = z ? b2b : b2a;
    float*          Cp = z ? a1 : a0;
    const int ldbz = z ? 512 : 256;
    gemm_core<0>(Ap, 768, Wp, ldbz, bp, nullptr, Cp, nullptr, 1024, ldbz,
                 blockIdx.x, blockIdx.y);
}

// ---------------------------------------------------------------------------
// Weight transpose+convert: W[K,N] f32 -> Wt[N,K] bf16.
// ---------------------------------------------------------------------------
__device__ __forceinline__ void wtrans_core(
    const float* __restrict__ W, ushort_t* __restrict__ Wt, int K, int N,
    int bx, int by)
{
    __shared__ float tile[32][33];
    const int n0 = bx * 32, k0 = by * 32;
    const int tx = threadIdx.x & 31, ty = threadIdx.x >> 5;
    #pragma unroll
    for (int j = 0; j < 4; ++j)
        tile[ty + j * 8][tx] = W[(size_t)(k0 + ty + j * 8) * N + n0 + tx];
    __syncthreads();
    #pragma unroll
    for (int j = 0; j < 4; ++j)
        Wt[(size_t)(n0 + ty + j * 8) * K + k0 + tx] = f2b(tile[tx][ty + j * 8]);
}

__global__ __launch_bounds__(256) void wtrans(
    const float* __restrict__ W, ushort_t* __restrict__ Wt, int K, int N)
{
    wtrans_core(W, Wt, K, N, blockIdx.x, blockIdx.y);
}

__global__ __launch_bounds__(256) void wtrans4(
    const float* w0, const float* w1, const float* w2, const float* w3,
    ushort_t* d0, ushort_t* d1, ushort_t* d2, ushort_t* d3)
{
    const int z = blockIdx.z;
    const float* W = (z == 0) ? w0 : (z == 1) ? w1 : (z == 2) ? w2 : w3;
    ushort_t* Wt   = (z == 0) ? d0 : (z == 1) ? d1 : (z == 2) ? d2 : d3;
    wtrans_core(W, Wt, 1024, 1024, blockIdx.x, blockIdx.y);
}

__global__ __launch_bounds__(256) void conv_f2b(
    const float* __restrict__ in, ushort_t* __restrict__ out, int n4)
{
    const int i = blockIdx.x * 256 + threadIdx.x;
    if (i >= n4) return;
    float4 v = ((const float4*)in)[i];
    ushort4 o; o.x = f2b(v.x); o.y = f2b(v.y); o.z = f2b(v.z); o.w = f2b(v.w);
    ((ushort4*)out)[i] = o;
}

__global__ __launch_bounds__(256) void prep_bias(
    const float* bq, const float* bk, const float* bv,
    const float* b1, const float* b2, float* bqkv, float* bad)
{
    const int t = blockIdx.x * 256 + threadIdx.x;
    if (t < 1024) { bqkv[t] = bq[t]; bqkv[1024 + t] = bk[t]; bqkv[2048 + t] = bv[t]; }
    if (t < 256) bad[t] = b1[t];
    if (t < 512) bad[256 + t] = b2[t];
}

// ---------------------------------------------------------------------------
// Per-head LN (q,k) + copy (v), f32 strided qkv -> bf16 head-major planes.
// q is pre-scaled by 1/sqrt(DH)=0.125. One wave per (sel, tok, head).
// ---------------------------------------------------------------------------
__global__ __launch_bounds__(256) void ln_head4(
    const float* __restrict__ qkv,
    const float* __restrict__ qg, const float* __restrict__ qb,
    const float* __restrict__ kg, const float* __restrict__ kb,
    ushort_t* __restrict__ qh, ushort_t* __restrict__ kh, ushort_t* __restrict__ vh)
{
    const int gw   = (blockIdx.x * 256 + threadIdx.x) >> 6;
    const int lane = threadIdx.x & 63;
    const int sel  = gw >> 16;            // 0=q, 1=k, 2=v
    const int rem  = gw & 65535;
    const int tok  = rem >> 4;
    const int hh   = rem & 15;
    const float v = qkv[(size_t)tok * 3072 + sel * 1024 + hh * 64 + lane];
    const int bb = tok >> 11, ss = tok & 2047;
    const size_t dst = (((size_t)(bb * NH_ + hh)) * S_ + ss) * 64 + lane;
    if (sel == 2) { vh[dst] = f2b(v); return; }
    float s = v;
    #pragma unroll
    for (int o = 32; o >= 1; o >>= 1) s += __shfl_xor(s, o);
    const float mean = s * (1.0f / 64.0f);
    const float d = v - mean;
    float s2 = d * d;
    #pragma unroll
    for (int o = 32; o >= 1; o >>= 1) s2 += __shfl_xor(s2, o);
    const float r = d * rsqrtf(s2 * (1.0f / 64.0f) + 1e-5f);
    if (sel == 0) qh[dst] = f2b((r * qg[lane] + qb[lane]) * 0.125f);
    else          kh[dst] = f2b(r * kg[lane] + kb[lane]);
}

// ---------------------------------------------------------------------------
// MFMA flash attention. Block = (b, h, 64 queries), 4 waves x 16 q.
// Key tiles of 64 staged in LDS: K[key][d^swz(key)], Vt[d][key^swz(d)].
// Swapped QK^T: S[key][q] = mfma(K_frag, Q_frag) -> lane owns 16 scores for
// q=lane&15. P bounced via per-wave LDS to A-frag layout; PV = mfma(P, Vt).
// ---------------------------------------------------------------------------
__global__ __launch_bounds__(256) void attn_mfma(
    const ushort_t* __restrict__ qh, const ushort_t* __restrict__ kh,
    const ushort_t* __restrict__ vh, ushort_t* __restrict__ o)
{
    __shared__ __align__(16) ushort_t Ks[64 * 64];
    __shared__ __align__(16) ushort_t Vt[64 * 64];
    __shared__ __align__(16) ushort_t Pl[4 * 16 * 64];

    const int bid = blockIdx.x;
    const int qt  = bid & 31;            // 64-query tile index
    const int hh  = (bid >> 5) & 15;
    const int b   = bid >> 9;
    const int wq   = threadIdx.x >> 6;   // wave 0..3
    const int lane = threadIdx.x & 63;
    const int lg  = lane >> 4;
    const int lq  = lane & 15;

    const int i0  = qt * 64;
    const int iw0 = i0 + wq * 16;
    const int i_l = iw0 + lq;            // this lane's query (softmax regs)

    const size_t plane = ((size_t)(b * NH_ + hh)) * S_ * 64;

    // Q fragments (B-style): entity q = lane&15, k = lg*8+j (+32)
    s16x8 qf[2];
    {
        const ushort_t* qp = qh + plane + (size_t)(iw0 + lq) * 64 + lg * 8;
        qf[0] = *(const s16x8*)(qp);
        qf[1] = *(const s16x8*)(qp + 32);
    }

    f32x4 acc[4] = {};                   // out[q=lg*4+r][d=lq+16*dt]
    float M = -1e30f, L = 0.0f;

    const int jstart = (i0 - WIN_) > 0 ? (i0 - WIN_) : 0;
    const int nt     = (i0 + 64 - jstart) >> 6;

    // staging: 256 threads cover 32 rows/pass x 8 chunks; 2 passes = 64 rows
    const int srow0 = threadIdx.x >> 3;      // 0..31
    const int sd0   = (threadIdx.x & 7) * 8; // d offset

    for (int t = 0; t < nt; ++t) {
        const int j0 = jstart + t * 64;

        // ---- stage K and Vt (64 keys x 64 d), 2 passes ----
        #pragma unroll
        for (int pass = 0; pass < 2; ++pass) {
            const int skey = srow0 + pass * 32;
            const size_t src = plane + (size_t)(j0 + skey) * 64 + sd0;
            s16x8 k8 = *(const s16x8*)(kh + src);
            s16x8 v8 = *(const s16x8*)(vh + src);
            *(s16x8*)&Ks[skey * 64 + (sd0 ^ ((skey & 7) << 3))] = k8;
            #pragma unroll
            for (int e = 0; e < 8; ++e) {
                const int d = sd0 + e;
                Vt[d * 64 + (skey ^ (((d >> 1) & 7) << 3))] = (ushort_t)v8[e];
            }
        }
        __syncthreads();

        // ---- QK^T: sc[kt][r] = S[key=kt*16+lg*4+r][q=lq] ----
        f32x4 sc[4];
        #pragma unroll
        for (int kt = 0; kt < 4; ++kt) {
            const int krow = kt * 16 + lq;
            const int swk = (krow & 7) << 3;
            s16x8 k0 = *(const s16x8*)&Ks[krow * 64 + ((lg * 8) ^ swk)];
            s16x8 k1 = *(const s16x8*)&Ks[krow * 64 + ((lg * 8 + 32) ^ swk)];
            f32x4 z = {};
            z = __builtin_amdgcn_mfma_f32_16x16x32_bf16(k0, qf[0], z, 0, 0, 0);
            z = __builtin_amdgcn_mfma_f32_16x16x32_bf16(k1, qf[1], z, 0, 0, 0);
            sc[kt] = z;
        }

        // ---- mask + online softmax (per-lane state for q=lq) ----
        const bool fullv = (j0 + 63 <= iw0) && (iw0 + 15 - j0 <= WIN_);
        if (!fullv) {
            #pragma unroll
            for (int kt = 0; kt < 4; ++kt)
                #pragma unroll
                for (int r = 0; r < 4; ++r) {
                    const int jv = j0 + kt * 16 + lg * 4 + r;
                    const int dd = i_l - jv;
                    const bool ok = (dd >= 0) && (dd <= WIN_);
                    sc[kt][r] = ok ? sc[kt][r] : -1e30f;
                }
        }
        float mx = -1e30f;
        #pragma unroll
        for (int kt = 0; kt < 4; ++kt)
            #pragma unroll
            for (int r = 0; r < 4; ++r) mx = fmaxf(mx, sc[kt][r]);
        mx = fmaxf(mx, __shfl_xor(mx, 16));
        mx = fmaxf(mx, __shfl_xor(mx, 32));
        const float nM = fmaxf(M, mx);
        const float alpha = __expf(M - nM);
        M = nM;
        float ts = 0.0f;
        float ev[16];
        #pragma unroll
        for (int kt = 0; kt < 4; ++kt)
            #pragma unroll
            for (int r = 0; r < 4; ++r) {
                float e = __expf(sc[kt][r] - nM);
                if (!fullv) e = (sc[kt][r] > -1e29f) ? e : 0.0f;
                ev[kt * 4 + r] = e;
                ts += e;
            }
        ts += __shfl_xor(ts, 16);
        ts += __shfl_xor(ts, 32);
        L = L * alpha + ts;

        // ---- P -> per-wave LDS (A-frag layout [q][key], swizzled) ----
        {
            ushort_t* pw = Pl + wq * 1024;
            const int swq = (lq & 7) << 3;
            #pragma unroll
            for (int kt = 0; kt < 4; ++kt)
                #pragma unroll
                for (int pr = 0; pr < 2; ++pr) {
                    const int key0 = kt * 16 + lg * 4 + pr * 2;
                    const unsigned int pk =
                        (unsigned int)f2b(ev[kt * 4 + pr * 2]) |
                        ((unsigned int)f2b(ev[kt * 4 + pr * 2 + 1]) << 16);
                    *(unsigned int*)&pw[lq * 64 + (key0 ^ swq)] = pk;
                }
        }

        // ---- rescale acc by alpha (per output row q = lg*4+r) ----
        float ar[4];
        #pragma unroll
        for (int r = 0; r < 4; ++r) ar[r] = __shfl(alpha, lg * 4 + r);
        #pragma unroll
        for (int dt = 0; dt < 4; ++dt)
            #pragma unroll
            for (int r = 0; r < 4; ++r) acc[dt][r] *= ar[r];

        // ---- PV: acc[dt] += P[q][keys] x V[keys][d] ----
        {
            const ushort_t* pw = Pl + wq * 1024;
            const int swq = (lq & 7) << 3;
            s16x8 pf0 = *(const s16x8*)&pw[lq * 64 + ((lg * 8) ^ swq)];
            s16x8 pf1 = *(const s16x8*)&pw[lq * 64 + ((lg * 8 + 32) ^ swq)];
            #pragma unroll
            for (int dt = 0; dt < 4; ++dt) {
                const int d = dt * 16 + lq;
                const int swd = ((d >> 1) & 7) << 3;
                s16x8 v0 = *(const s16x8*)&Vt[d * 64 + ((lg * 8) ^ swd)];
                s16x8 v1 = *(const s16x8*)&Vt[d * 64 + ((lg * 8 + 32) ^ swd)];
                acc[dt] = __builtin_amdgcn_mfma_f32_16x16x32_bf16(pf0, v0, acc[dt], 0, 0, 0);
                acc[dt] = __builtin_amdgcn_mfma_f32_16x16x32_bf16(pf1, v1, acc[dt], 0, 0, 0);
            }
        }
        __syncthreads();
    }

    // ---- finalize: out = acc / L, token-major bf16 ----
    const float inv = 1.0f / L;
    float ir[4];
    #pragma unroll
    for (int r = 0; r < 4; ++r) ir[r] = __shfl(inv, lg * 4 + r);
    #pragma unroll
    for (int dt = 0; dt < 4; ++dt)
        #pragma unroll
        for (int r = 0; r < 4; ++r) {
            const int qq = lg * 4 + r;
            o[((size_t)(b * S_ + iw0 + qq)) * DM_ + hh * 64 + dt * 16 + lq] =
                f2b(acc[dt][r] * ir[r]);
        }
}

// ---------------------------------------------------------------------------
// Token LayerNorm: in (f32 or bf16) -> bf16. One block per token.
// ---------------------------------------------------------------------------
template <int N, typename TI>
__global__ __launch_bounds__(256) void ln_token2(
    const TI* __restrict__ in, ushort_t* __restrict__ outp,
    const float* __restrict__ g, const float* __restrict__ b)
{
    constexpr int NPT = N / 256;
    const int t = blockIdx.x;
    const TI* row = in + (size_t)t * N;
    float vals[NPT];
    float s = 0.0f, s2 = 0.0f;
    #pragma unroll
    for (int i = 0; i < NPT; ++i) {
        float x;
        if (sizeof(TI) == 2) x = b2f(((const ushort_t*)row)[i * 256 + threadIdx.x]);
        else                 x = ((const float*)row)[i * 256 + threadIdx.x];
        vals[i] = x;
        s += x;
        s2 = fmaf(x, x, s2);
    }
    #pragma unroll
    for (int o = 32; o >= 1; o >>= 1) { s += __shfl_xor(s, o); s2 += __shfl_xor(s2, o); }
    __shared__ float rs[4], rq[4];
    const int wid = threadIdx.x >> 6, lane = threadIdx.x & 63;
    if (lane == 0) { rs[wid] = s; rq[wid] = s2; }
    __syncthreads();
    s  = rs[0] + rs[1] + rs[2] + rs[3];
    s2 = rq[0] + rq[1] + rq[2] + rq[3];
    const float mean = s * (1.0f / N);
    const float var  = s2 * (1.0f / N) - mean * mean;
    const float rstd = rsqrtf(var + 1e-5f);
    #pragma unroll
    for (int i = 0; i < NPT; ++i) {
        const int idx = i * 256 + threadIdx.x;
        outp[(size_t)t * N + idx] = f2b((vals[i] - mean) * rstd * g[idx] + b[idx]);
    }
}

// ---------------------------------------------------------------------------
// Final combine: out = h + (p0+p1+fc2_b)*wm + adaptive*(1-wm).
// ---------------------------------------------------------------------------
__global__ __launch_bounds__(256) void combine3(
    float* __restrict__ outp, const float* __restrict__ p1,
    const float* __restrict__ fc2b, const float* __restrict__ h,
    const ushort_t* __restrict__ xnb, const float* __restrict__ a0,
    const float* __restrict__ a1, const float* __restrict__ wm,
    const int* __restrict__ widx)
{
    const size_t idx = (size_t)blockIdx.x * 256 + threadIdx.x;
    const int t   = (int)(idx >> 10);
    const int col = (int)(idx & 1023);
    const float w = wm[t];
    const int sel = widx[t];
    const float base = outp[idx] + p1[idx] + fc2b[col];
    const float ad = (sel == 0) ? a0[idx] : ((sel == 1) ? a1[idx] : b2f(xnb[idx]));
    outp[idx] = h[idx] + base * w + ad * (1.0f - w);
}

// ---------------------------------------------------------------------------
extern "C" void kernel_launch(void* const* d_in, const int* in_sizes, int n_in,
                              void* d_out, int out_size, void* d_ws, size_t ws_size,
                              hipStream_t stream)
{
    const float* x     = (const float*)d_in[0];
    const float* wm    = (const float*)d_in[1];
    const float* wq    = (const float*)d_in[2];
    const float* bq    = (const float*)d_in[3];
    const float* wk    = (const float*)d_in[4];
    const float* bk    = (const float*)d_in[5];
    const float* wv    = (const float*)d_in[6];
    const float* bv    = (const float*)d_in[7];
    const float* wo    = (const float*)d_in[8];
    const float* bo    = (const float*)d_in[9];
    const float* lnq_g = (const float*)d_in[10];
    const float* lnq_b = (const float*)d_in[11];
    const float* lnk_g = (const float*)d_in[12];
    const float* lnk_b = (const float*)d_in[13];
    const float* fc1_w = (const float*)d_in[14];
    const float* fc1_b = (const float*)d_in[15];
    const float* fc2_w = (const float*)d_in[16];
    const float* fc2_b = (const float*)d_in[17];
    const float* lni_g = (const float*)d_in[18];
    const float* lni_b = (const float*)d_in[19];
    const float* lnh_g = (const float*)d_in[20];
    const float* lnh_b = (const float*)d_in[21];
    const float* a256_w1 = (const float*)d_in[22];
    const float* a256_b1 = (const float*)d_in[23];
    const float* a256_w2 = (const float*)d_in[24];
    const float* a256_b2 = (const float*)d_in[25];
    const float* a512_w1 = (const float*)d_in[26];
    const float* a512_b1 = (const float*)d_in[27];
    const float* a512_w2 = (const float*)d_in[28];
    const float* a512_b2 = (const float*)d_in[29];
    const int*   widx    = (const int*)d_in[30];

    float* out = (float*)d_out;

    char* p = (char*)d_ws;
    auto alloc = [&](size_t bytes) { char* r = p; p += (bytes + 255) & ~(size_t)255; return r; };
    float*    qkv   = (float*)   alloc((size_t)MTOK * 3072 * 4);  // a0/a1 alias later
    float*    hb    = (float*)   alloc((size_t)MTOK * 1024 * 4);
    ushort_t* xnb   = (ushort_t*)alloc((size_t)MTOK * 1024 * 2);
    ushort_t* hidb  = (ushort_t*)alloc((size_t)MTOK * 4096 * 2);  // xb/attnb/qh/kh alias
    ushort_t* tA    = (ushort_t*)alloc((size_t)MTOK * 768 * 2);
    ushort_t* WqkvT = (ushort_t*)alloc((size_t)3072 * 1024 * 2);
    ushort_t* WoT   = (ushort_t*)alloc((size_t)1024 * 1024 * 2);
    ushort_t* fc1T  = (ushort_t*)alloc((size_t)4096 * 1024 * 2);
    ushort_t* fc2T  = (ushort_t*)alloc((size_t)1024 * 4096 * 2);
    ushort_t* Wad1T = (ushort_t*)alloc((size_t)768 * 1024 * 2);
    ushort_t* w2aT  = (ushort_t*)alloc((size_t)1024 * 256 * 2);
    ushort_t* w2bT  = (ushort_t*)alloc((size_t)1024 * 512 * 2);
    float*    bqkv  = (float*)   alloc(3072 * 4);
    float*    bad   = (float*)   alloc(768 * 4);
    float*    p1    = (float*)   alloc((size_t)MTOK * 1024 * 4);  // fc2 partial / vh alias
    // aliases (lifetimes verified):
    //  xb    = hidb[0 : 4.19M)      dead after qkv GEMM
    //  attnb = hidb[4.19M : 8.39M)  written by attn, dead after wo GEMM
    //  qh/kh = hidb[8.39M : 16.8M)  written by ln_head4, dead after attn
    //  (all dead before fc1 writes hidb)
    //  vh    = p1 region            dead before fc2_sk writes p1
    //  a0/a1 = qkv region           qkv dead after ln_head4
    ushort_t* xb    = hidb;
    ushort_t* attnb = hidb + (size_t)MTOK * 1024;
    ushort_t* qh    = hidb + (size_t)MTOK * 2048;
    ushort_t* kh    = hidb + (size_t)MTOK * 3072;
    ushort_t* vh    = (ushort_t*)p1;
    float*    a0    = qkv;
    float*    a1    = qkv + (size_t)MTOK * 1024;

    const dim3 blk(256);

    // ---- prep ----
    prep_bias<<<4, blk, 0, stream>>>(bq, bk, bv, a256_b1, a512_b1, bqkv, bad);
    conv_f2b<<<(MTOK * 1024 / 4 + 255) / 256, blk, 0, stream>>>(x, xb, MTOK * 1024 / 4);
    wtrans4<<<dim3(32, 32, 4), blk, 0, stream>>>(wq, wk, wv, wo,
        WqkvT, WqkvT + 1024 * 1024, WqkvT + 2048 * 1024, WoT);
    wtrans<<<dim3(128, 32), blk, 0, stream>>>(fc1_w, fc1T, 1024, 4096);
    wtrans<<<dim3(32, 128), blk, 0, stream>>>(fc2_w, fc2T, 4096, 1024);
    wtrans<<<dim3(8, 32),   blk, 0, stream>>>(a256_w1, Wad1T, 1024, 256);
    wtrans<<<dim3(16, 32),  blk, 0, stream>>>(a512_w1, Wad1T + 256 * 1024, 1024, 512);
    wtrans<<<dim3(32, 8),   blk, 0, stream>>>(a256_w2, w2aT, 256, 1024);
    wtrans<<<dim3(32, 16),  blk, 0, stream>>>(a512_w2, w2bT, 512, 1024);

    // ---- QKV projection + per-head LN/relayout + MFMA attention ----
    gemm_mfma<0><<<dim3(24, 32), blk, 0, stream>>>(xb, 1024, WqkvT, bqkv, nullptr,
                                                   qkv, nullptr, MTOK, 3072, 1024);
    ln_head4<<<3 * 65536 / 4, blk, 0, stream>>>(qkv, lnq_g, lnq_b, lnk_g, lnk_b,
                                                qh, kh, vh);
    attn_mfma<<<B_ * NH_ * (S_ / 64), blk, 0, stream>>>(qh, kh, vh, attnb);

    // ---- output projection + residual -> h (f32) ----
    gemm_mfma<0><<<dim3(8, 32), blk, 0, stream>>>(attnb, 1024, WoT, bo, x,
                                                  hb, nullptr, MTOK, 1024, 1024);
    ln_token2<DM_, float><<<MTOK, blk, 0, stream>>>(hb, xnb, lni_g, lni_b);

    // ---- base FFN ----
    gemm_mfma<1><<<dim3(32, 32), blk, 0, stream>>>(xnb, 1024, fc1T, fc1_b, nullptr,
                                                   nullptr, hidb, MTOK, 4096, 1024);
    ln_token2<DFF_, ushort_t><<<MTOK, blk, 0, stream>>>(hidb, hidb, lnh_g, lnh_b);
    gemm_fc2_sk<<<dim3(8, 32, 2), blk, 0, stream>>>(hidb, fc2T, out, p1);

    // ---- adapters ----
    gemm_mfma<1><<<dim3(6, 32), blk, 0, stream>>>(xnb, 1024, Wad1T, bad, nullptr,
                                                  nullptr, tA, MTOK, 768, 1024);
    gemm_adapters<<<dim3(8, 32, 2), blk, 0, stream>>>(tA, w2aT, w2bT,
                                                      a256_b2, a512_b2, a0, a1);

    // ---- final routed combine ----
    combine3<<<(int)((size_t)MTOK * 1024 / 256), blk, 0, stream>>>(
        out, p1, fc2_b, hb, xnb, a0, a1, wm, widx);
}

// Round 7
// 368.786 us; speedup vs baseline: 7.6046x; 1.0360x over previous
//
#include <hip/hip_runtime.h>
#include <math.h>

#define B_   2
#define S_   2048
#define DM_  1024
#define NH_  16
#define DH_  64
#define DFF_ 4096
#define WIN_ 256
#define MTOK (B_*S_)   // 4096 tokens

typedef unsigned short ushort_t;
typedef short s16x8 __attribute__((ext_vector_type(8)));
typedef float f32x4 __attribute__((ext_vector_type(4)));

__device__ __forceinline__ float b2f(ushort_t u) {
    union { unsigned int i; float f; } c; c.i = ((unsigned int)u) << 16; return c.f;
}
__device__ __forceinline__ ushort_t f2b(float f) {
    union { float f; unsigned int i; } c; c.f = f;
    unsigned int r = c.i + 0x7fffu + ((c.i >> 16) & 1u);   // RNE
    return (ushort_t)(r >> 16);
}
// tanh-form GELU: |err| vs exact erf-GELU < 3e-3 absolute (<< bf16 noise here)
__device__ __forceinline__ float gelu_fast(float x) {
    const float u = 0.7978845608f * x * fmaf(0.044715f, x * x, 1.0f);
    const float e = __expf(2.0f * u);
    const float t = 1.0f - 2.0f / (e + 1.0f);   // tanh(u)
    return 0.5f * x * (1.0f + t);
}
__device__ __forceinline__ void gload16(const void* g, void* l) {
    __builtin_amdgcn_global_load_lds(
        (const __attribute__((address_space(1))) unsigned int*)g,
        (__attribute__((address_space(3))) unsigned int*)l, 16, 0, 0);
}
// bijective XCD-aware block swizzle (m204): consecutive new ids live on one XCD
__device__ __forceinline__ int xcd_swz(int wgid, int nwg) {
    const int nx = 8;
    const int q = nwg / nx, r = nwg % nx;
    const int xcd = wgid % nx, lo = wgid / nx;
    const int base = (xcd < r) ? xcd * (q + 1) : r * (q + 1) + (xcd - r) * q;
    return base + lo;
}

// ---------------------------------------------------------------------------
// bf16 MFMA GEMM core (m97 structure): 128x128 tile, BK=64, 4 waves.
// ACT: 0=bias(+res), 1=gelu(bias)(+res), 2=raw partial.
// ---------------------------------------------------------------------------
template <int ACT>
__device__ __forceinline__ void gemm_core(
    const ushort_t* __restrict__ A, int lda,
    const ushort_t* __restrict__ Bt, int ldb,
    const float* __restrict__ bias, const float* __restrict__ res,
    float* __restrict__ Cf, ushort_t* __restrict__ Cb,
    int N, int Kc, int bx, int by)
{
    __shared__ __align__(16) ushort_t As[128 * 64];
    __shared__ __align__(16) ushort_t Bs[128 * 64];

    const int tid  = threadIdx.x;
    const int lane = tid & 63;
    const int w    = tid >> 6;
    const int row0 = by * 128;
    const int col0 = bx * 128;

    const int srow = lane >> 3;
    const int sk   = (lane & 7) * 8;
    const int wr   = (w >> 1) * 64;
    const int wc   = (w & 1) * 64;
    const int lr   = lane & 15;
    const int lk   = (lane >> 4) * 8;

    f32x4 acc[4][4] = {};

    for (int k0 = 0; k0 < Kc; k0 += 64) {
        #pragma unroll
        for (int i = 0; i < 4; ++i) {
            const int c = i * 4 + w;
            const int cr = c * 8 + srow;
            gload16(A  + (size_t)(row0 + cr) * lda + k0 + sk, (char*)As + c * 1024);
            gload16(Bt + (size_t)(col0 + cr) * ldb + k0 + sk, (char*)Bs + c * 1024);
        }
        __syncthreads();
        #pragma unroll
        for (int ks = 0; ks < 2; ++ks) {
            s16x8 af[4], bfr[4];
            #pragma unroll
            for (int mi = 0; mi < 4; ++mi)
                af[mi] = *(const s16x8*)&As[(wr + mi * 16 + lr) * 64 + ks * 32 + lk];
            #pragma unroll
            for (int ni = 0; ni < 4; ++ni)
                bfr[ni] = *(const s16x8*)&Bs[(wc + ni * 16 + lr) * 64 + ks * 32 + lk];
            #pragma unroll
            for (int mi = 0; mi < 4; ++mi)
                #pragma unroll
                for (int ni = 0; ni < 4; ++ni)
                    acc[mi][ni] = __builtin_amdgcn_mfma_f32_16x16x32_bf16(
                        af[mi], bfr[ni], acc[mi][ni], 0, 0, 0);
        }
        __syncthreads();
    }

    const int crow = (lane >> 4) * 4;
    const int ccol = lane & 15;
    #pragma unroll
    for (int ni = 0; ni < 4; ++ni) {
        const int col = col0 + wc + ni * 16 + ccol;
        const float bc = (ACT == 2) ? 0.0f : bias[col];
        #pragma unroll
        for (int mi = 0; mi < 4; ++mi) {
            #pragma unroll
            for (int r = 0; r < 4; ++r) {
                const int row = row0 + wr + mi * 16 + crow + r;
                float v = acc[mi][ni][r] + bc;
                if (ACT == 1) v = gelu_fast(v);
                const size_t idx = (size_t)row * N + col;
                if (ACT != 2 && res) v += res[idx];
                if (Cf) Cf[idx] = v;
                if (ACT != 2 && Cb) Cb[idx] = f2b(v);
            }
        }
    }
}

template <int ACT>
__global__ __launch_bounds__(256) void gemm_mfma(
    const ushort_t* __restrict__ A, int lda,
    const ushort_t* __restrict__ Bt,
    const float* __restrict__ bias, const float* __restrict__ res,
    float* __restrict__ Cf, ushort_t* __restrict__ Cb,
    int M, int N, int K)
{
    const int s = xcd_swz(blockIdx.y * gridDim.x + blockIdx.x, gridDim.x * gridDim.y);
    gemm_core<ACT>(A, lda, Bt, K, bias, res, Cf, Cb, N, K, s % gridDim.x, s / gridDim.x);
}

__global__ __launch_bounds__(256) void gemm_fc2_sk(
    const ushort_t* __restrict__ A, const ushort_t* __restrict__ Bt,
    float* __restrict__ p0, float* __restrict__ p1)
{
    const int z = blockIdx.z;
    const int s = xcd_swz(blockIdx.y * gridDim.x + blockIdx.x, gridDim.x * gridDim.y);
    gemm_core<2>(A + z * 2048, 4096, Bt + z * 2048, 4096, nullptr, nullptr,
                 z ? p1 : p0, nullptr, 1024, 2048, s % gridDim.x, s / gridDim.x);
}

// wo with split-K=2: raw partials p0/p1 (bias+residual folded into ln_token_h)
__global__ __launch_bounds__(256) void gemm_wo_sk(
    const ushort_t* __restrict__ A, const ushort_t* __restrict__ Wt,
    float* __restrict__ p0, float* __restrict__ p1)
{
    const int z = blockIdx.z;
    const int s = xcd_swz(blockIdx.y * gridDim.x + blockIdx.x, gridDim.x * gridDim.y);
    gemm_core<2>(A + z * 512, 1024, Wt + z * 512, 1024, nullptr, nullptr,
                 z ? p1 : p0, nullptr, 1024, 512, s % gridDim.x, s / gridDim.x);
}

__global__ __launch_bounds__(256) void gemm_adapters(
    const ushort_t* __restrict__ tA, const ushort_t* __restrict__ w2a,
    const ushort_t* __restrict__ w2b, const float* __restrict__ b2a,
    const float* __restrict__ b2b, float* __restrict__ a0, float* __restrict__ a1)
{
    const int z = blockIdx.z;
    const ushort_t* Ap = z ? tA + 256 : tA;
    const ushort_t* Wp = z ? w2b : w2a;
    const float*    bp = z ? b2b : b2a;
    float*          Cp = z ? a1 : a0;
    const int ldbz = z ? 512 : 256;
    const int s = xcd_swz(blockIdx.y * gridDim.x + blockIdx.x, gridDim.x * gridDim.y);
    gemm_core<0>(Ap, 768, Wp, ldbz, bp, nullptr, Cp, nullptr, 1024, ldbz,
                 s % gridDim.x, s / gridDim.x);
}

// ---------------------------------------------------------------------------
// Weight transpose+convert: W[K,N] f32 -> Wt[N,K] bf16.
// ---------------------------------------------------------------------------
__device__ __forceinline__ void wtrans_core(
    const float* __restrict__ W, ushort_t* __restrict__ Wt, int K, int N,
    int bx, int by)
{
    __shared__ float tile[32][33];
    const int n0 = bx * 32, k0 = by * 32;
    const int tx = threadIdx.x & 31, ty = threadIdx.x >> 5;
    #pragma unroll
    for (int j = 0; j < 4; ++j)
        tile[ty + j * 8][tx] = W[(size_t)(k0 + ty + j * 8) * N + n0 + tx];
    __syncthreads();
    #pragma unroll
    for (int j = 0; j < 4; ++j)
        Wt[(size_t)(n0 + ty + j * 8) * K + k0 + tx] = f2b(tile[tx][ty + j * 8]);
}

__global__ __launch_bounds__(256) void wtrans(
    const float* __restrict__ W, ushort_t* __restrict__ Wt, int K, int N)
{
    wtrans_core(W, Wt, K, N, blockIdx.x, blockIdx.y);
}

__global__ __launch_bounds__(256) void wtrans4(
    const float* w0, const float* w1, const float* w2, const float* w3,
    ushort_t* d0, ushort_t* d1, ushort_t* d2, ushort_t* d3)
{
    const int z = blockIdx.z;
    const float* W = (z == 0) ? w0 : (z == 1) ? w1 : (z == 2) ? w2 : w3;
    ushort_t* Wt   = (z == 0) ? d0 : (z == 1) ? d1 : (z == 2) ? d2 : d3;
    wtrans_core(W, Wt, 1024, 1024, blockIdx.x, blockIdx.y);
}

__global__ __launch_bounds__(256) void conv_f2b(
    const float* __restrict__ in, ushort_t* __restrict__ out, int n4)
{
    const int i = blockIdx.x * 256 + threadIdx.x;
    if (i >= n4) return;
    float4 v = ((const float4*)in)[i];
    ushort4 o; o.x = f2b(v.x); o.y = f2b(v.y); o.z = f2b(v.z); o.w = f2b(v.w);
    ((ushort4*)out)[i] = o;
}

__global__ __launch_bounds__(256) void prep_bias(
    const float* bq, const float* bk, const float* bv,
    const float* b1, const float* b2, float* bqkv, float* bad)
{
    const int t = blockIdx.x * 256 + threadIdx.x;
    if (t < 1024) { bqkv[t] = bq[t]; bqkv[1024 + t] = bk[t]; bqkv[2048 + t] = bv[t]; }
    if (t < 256) bad[t] = b1[t];
    if (t < 512) bad[256 + t] = b2[t];
}

// ---------------------------------------------------------------------------
// Per-head LN (q,k) + copy (v), f32 strided qkv -> bf16 head-major planes.
// q is pre-scaled by 1/sqrt(DH)=0.125. One wave per (sel, tok, head).
// ---------------------------------------------------------------------------
__global__ __launch_bounds__(256) void ln_head4(
    const float* __restrict__ qkv,
    const float* __restrict__ qg, const float* __restrict__ qb,
    const float* __restrict__ kg, const float* __restrict__ kb,
    ushort_t* __restrict__ qh, ushort_t* __restrict__ kh, ushort_t* __restrict__ vh)
{
    const int gw   = (blockIdx.x * 256 + threadIdx.x) >> 6;
    const int lane = threadIdx.x & 63;
    const int sel  = gw >> 16;            // 0=q, 1=k, 2=v
    const int rem  = gw & 65535;
    const int tok  = rem >> 4;
    const int hh   = rem & 15;
    const float v = qkv[(size_t)tok * 3072 + sel * 1024 + hh * 64 + lane];
    const int bb = tok >> 11, ss = tok & 2047;
    const size_t dst = (((size_t)(bb * NH_ + hh)) * S_ + ss) * 64 + lane;
    if (sel == 2) { vh[dst] = f2b(v); return; }
    float s = v;
    #pragma unroll
    for (int o = 32; o >= 1; o >>= 1) s += __shfl_xor(s, o);
    const float mean = s * (1.0f / 64.0f);
    const float d = v - mean;
    float s2 = d * d;
    #pragma unroll
    for (int o = 32; o >= 1; o >>= 1) s2 += __shfl_xor(s2, o);
    const float r = d * rsqrtf(s2 * (1.0f / 64.0f) + 1e-5f);
    if (sel == 0) qh[dst] = f2b((r * qg[lane] + qb[lane]) * 0.125f);
    else          kh[dst] = f2b(r * kg[lane] + kb[lane]);
}

// ---------------------------------------------------------------------------
// MFMA flash attention. Block = (b, h, 64 queries), 4 waves x 16 q.
// ---------------------------------------------------------------------------
__global__ __launch_bounds__(256) void attn_mfma(
    const ushort_t* __restrict__ qh, const ushort_t* __restrict__ kh,
    const ushort_t* __restrict__ vh, ushort_t* __restrict__ o)
{
    __shared__ __align__(16) ushort_t Ks[64 * 64];
    __shared__ __align__(16) ushort_t Vt[64 * 64];
    __shared__ __align__(16) ushort_t Pl[4 * 16 * 64];

    const int bid = xcd_swz(blockIdx.x, gridDim.x);
    const int qt  = bid & 31;            // 64-query tile index
    const int hh  = (bid >> 5) & 15;
    const int b   = bid >> 9;
    const int wq   = threadIdx.x >> 6;   // wave 0..3
    const int lane = threadIdx.x & 63;
    const int lg  = lane >> 4;
    const int lq  = lane & 15;

    const int i0  = qt * 64;
    const int iw0 = i0 + wq * 16;
    const int i_l = iw0 + lq;            // this lane's query (softmax regs)

    const size_t plane = ((size_t)(b * NH_ + hh)) * S_ * 64;

    // Q fragments (B-style): entity q = lane&15, k = lg*8+j (+32)
    s16x8 qf[2];
    {
        const ushort_t* qp = qh + plane + (size_t)(iw0 + lq) * 64 + lg * 8;
        qf[0] = *(const s16x8*)(qp);
        qf[1] = *(const s16x8*)(qp + 32);
    }

    f32x4 acc[4] = {};                   // out[q=lg*4+r][d=lq+16*dt]
    float M = -1e30f, L = 0.0f;

    const int jstart = (i0 - WIN_) > 0 ? (i0 - WIN_) : 0;
    const int nt     = (i0 + 64 - jstart) >> 6;

    // staging: 256 threads cover 32 rows/pass x 8 chunks; 2 passes = 64 rows
    const int srow0 = threadIdx.x >> 3;      // 0..31
    const int sd0   = (threadIdx.x & 7) * 8; // d offset

    for (int t = 0; t < nt; ++t) {
        const int j0 = jstart + t * 64;

        // ---- stage K and Vt (64 keys x 64 d), 2 passes ----
        #pragma unroll
        for (int pass = 0; pass < 2; ++pass) {
            const int skey = srow0 + pass * 32;
            const size_t src = plane + (size_t)(j0 + skey) * 64 + sd0;
            s16x8 k8 = *(const s16x8*)(kh + src);
            s16x8 v8 = *(const s16x8*)(vh + src);
            *(s16x8*)&Ks[skey * 64 + (sd0 ^ ((skey & 7) << 3))] = k8;
            #pragma unroll
            for (int e = 0; e < 8; ++e) {
                const int d = sd0 + e;
                Vt[d * 64 + (skey ^ (((d >> 1) & 7) << 3))] = (ushort_t)v8[e];
            }
        }
        __syncthreads();

        // ---- QK^T: sc[kt][r] = S[key=kt*16+lg*4+r][q=lq] ----
        f32x4 sc[4];
        #pragma unroll
        for (int kt = 0; kt < 4; ++kt) {
            const int krow = kt * 16 + lq;
            const int swk = (krow & 7) << 3;
            s16x8 k0 = *(const s16x8*)&Ks[krow * 64 + ((lg * 8) ^ swk)];
            s16x8 k1 = *(const s16x8*)&Ks[krow * 64 + ((lg * 8 + 32) ^ swk)];
            f32x4 z = {};
            z = __builtin_amdgcn_mfma_f32_16x16x32_bf16(k0, qf[0], z, 0, 0, 0);
            z = __builtin_amdgcn_mfma_f32_16x16x32_bf16(k1, qf[1], z, 0, 0, 0);
            sc[kt] = z;
        }

        // ---- mask + online softmax (per-lane state for q=lq) ----
        const bool fullv = (j0 + 63 <= iw0) && (iw0 + 15 - j0 <= WIN_);
        if (!fullv) {
            #pragma unroll
            for (int kt = 0; kt < 4; ++kt)
                #pragma unroll
                for (int r = 0; r < 4; ++r) {
                    const int jv = j0 + kt * 16 + lg * 4 + r;
                    const int dd = i_l - jv;
                    const bool ok = (dd >= 0) && (dd <= WIN_);
                    sc[kt][r] = ok ? sc[kt][r] : -1e30f;
                }
        }
        float mx = -1e30f;
        #pragma unroll
        for (int kt = 0; kt < 4; ++kt)
            #pragma unroll
            for (int r = 0; r < 4; ++r) mx = fmaxf(mx, sc[kt][r]);
        mx = fmaxf(mx, __shfl_xor(mx, 16));
        mx = fmaxf(mx, __shfl_xor(mx, 32));
        const float nM = fmaxf(M, mx);
        const float alpha = __expf(M - nM);
        M = nM;
        float ts = 0.0f;
        float ev[16];
        #pragma unroll
        for (int kt = 0; kt < 4; ++kt)
            #pragma unroll
            for (int r = 0; r < 4; ++r) {
                float e = __expf(sc[kt][r] - nM);
                if (!fullv) e = (sc[kt][r] > -1e29f) ? e : 0.0f;
                ev[kt * 4 + r] = e;
                ts += e;
            }
        ts += __shfl_xor(ts, 16);
        ts += __shfl_xor(ts, 32);
        L = L * alpha + ts;

        // ---- P -> per-wave LDS (A-frag layout [q][key], swizzled) ----
        {
            ushort_t* pw = Pl + wq * 1024;
            const int swq = (lq & 7) << 3;
            #pragma unroll
            for (int kt = 0; kt < 4; ++kt)
                #pragma unroll
                for (int pr = 0; pr < 2; ++pr) {
                    const int key0 = kt * 16 + lg * 4 + pr * 2;
                    const unsigned int pk =
                        (unsigned int)f2b(ev[kt * 4 + pr * 2]) |
                        ((unsigned int)f2b(ev[kt * 4 + pr * 2 + 1]) << 16);
                    *(unsigned int*)&pw[lq * 64 + (key0 ^ swq)] = pk;
                }
        }

        // ---- rescale acc by alpha (per output row q = lg*4+r) ----
        float ar[4];
        #pragma unroll
        for (int r = 0; r < 4; ++r) ar[r] = __shfl(alpha, lg * 4 + r);
        #pragma unroll
        for (int dt = 0; dt < 4; ++dt)
            #pragma unroll
            for (int r = 0; r < 4; ++r) acc[dt][r] *= ar[r];

        // ---- PV: acc[dt] += P[q][keys] x V[keys][d] ----
        {
            const ushort_t* pw = Pl + wq * 1024;
            const int swq = (lq & 7) << 3;
            s16x8 pf0 = *(const s16x8*)&pw[lq * 64 + ((lg * 8) ^ swq)];
            s16x8 pf1 = *(const s16x8*)&pw[lq * 64 + ((lg * 8 + 32) ^ swq)];
            #pragma unroll
            for (int dt = 0; dt < 4; ++dt) {
                const int d = dt * 16 + lq;
                const int swd = ((d >> 1) & 7) << 3;
                s16x8 v0 = *(const s16x8*)&Vt[d * 64 + ((lg * 8) ^ swd)];
                s16x8 v1 = *(const s16x8*)&Vt[d * 64 + ((lg * 8 + 32) ^ swd)];
                acc[dt] = __builtin_amdgcn_mfma_f32_16x16x32_bf16(pf0, v0, acc[dt], 0, 0, 0);
                acc[dt] = __builtin_amdgcn_mfma_f32_16x16x32_bf16(pf1, v1, acc[dt], 0, 0, 0);
            }
        }
        __syncthreads();
    }

    // ---- finalize: out = acc / L, token-major bf16 ----
    const float inv = 1.0f / L;
    float ir[4];
    #pragma unroll
    for (int r = 0; r < 4; ++r) ir[r] = __shfl(inv, lg * 4 + r);
    #pragma unroll
    for (int dt = 0; dt < 4; ++dt)
        #pragma unroll
        for (int r = 0; r < 4; ++r) {
            const int qq = lg * 4 + r;
            o[((size_t)(b * S_ + iw0 + qq)) * DM_ + hh * 64 + dt * 16 + lq] =
                f2b(acc[dt][r] * ir[r]);
        }
}

// ---------------------------------------------------------------------------
// Fused h-assembly + token LayerNorm (N=1024):
// h = x + p0 + p1 + bo ; hb = h (f32) ; xnb = LN(h)*g+b (bf16).
// ---------------------------------------------------------------------------
__global__ __launch_bounds__(256) void ln_token_h(
    const float* __restrict__ p0, const float* __restrict__ p1,
    const float* __restrict__ bo, const float* __restrict__ x,
    float* __restrict__ hb, ushort_t* __restrict__ xnb,
    const float* __restrict__ g, const float* __restrict__ b)
{
    const int t = blockIdx.x;
    const size_t base = (size_t)t * 1024;
    float vals[4];
    float s = 0.0f, s2 = 0.0f;
    #pragma unroll
    for (int i = 0; i < 4; ++i) {
        const int idx = i * 256 + threadIdx.x;
        const float v = x[base + idx] + p0[base + idx] + p1[base + idx] + bo[idx];
        hb[base + idx] = v;
        vals[i] = v;
        s += v;
        s2 = fmaf(v, v, s2);
    }
    #pragma unroll
    for (int o = 32; o >= 1; o >>= 1) { s += __shfl_xor(s, o); s2 += __shfl_xor(s2, o); }
    __shared__ float rs[4], rq[4];
    const int wid = threadIdx.x >> 6, lane = threadIdx.x & 63;
    if (lane == 0) { rs[wid] = s; rq[wid] = s2; }
    __syncthreads();
    s  = rs[0] + rs[1] + rs[2] + rs[3];
    s2 = rq[0] + rq[1] + rq[2] + rq[3];
    const float mean = s * (1.0f / 1024.0f);
    const float var  = s2 * (1.0f / 1024.0f) - mean * mean;
    const float rstd = rsqrtf(var + 1e-5f);
    #pragma unroll
    for (int i = 0; i < 4; ++i) {
        const int idx = i * 256 + threadIdx.x;
        xnb[base + idx] = f2b((vals[i] - mean) * rstd * g[idx] + b[idx]);
    }
}

// ---------------------------------------------------------------------------
// Token LayerNorm: bf16 in -> bf16 out. One block per token.
// ---------------------------------------------------------------------------
template <int N>
__global__ __launch_bounds__(256) void ln_token2(
    const ushort_t* __restrict__ in, ushort_t* __restrict__ outp,
    const float* __restrict__ g, const float* __restrict__ b)
{
    constexpr int NPT = N / 256;
    const int t = blockIdx.x;
    const ushort_t* row = in + (size_t)t * N;
    float vals[NPT];
    float s = 0.0f, s2 = 0.0f;
    #pragma unroll
    for (int i = 0; i < NPT; ++i) {
        float x = b2f(row[i * 256 + threadIdx.x]);
        vals[i] = x;
        s += x;
        s2 = fmaf(x, x, s2);
    }
    #pragma unroll
    for (int o = 32; o >= 1; o >>= 1) { s += __shfl_xor(s, o); s2 += __shfl_xor(s2, o); }
    __shared__ float rs[4], rq[4];
    const int wid = threadIdx.x >> 6, lane = threadIdx.x & 63;
    if (lane == 0) { rs[wid] = s; rq[wid] = s2; }
    __syncthreads();
    s  = rs[0] + rs[1] + rs[2] + rs[3];
    s2 = rq[0] + rq[1] + rq[2] + rq[3];
    const float mean = s * (1.0f / N);
    const float var  = s2 * (1.0f / N) - mean * mean;
    const float rstd = rsqrtf(var + 1e-5f);
    #pragma unroll
    for (int i = 0; i < NPT; ++i) {
        const int idx = i * 256 + threadIdx.x;
        outp[(size_t)t * N + idx] = f2b((vals[i] - mean) * rstd * g[idx] + b[idx]);
    }
}

// ---------------------------------------------------------------------------
// Final combine: out = h + (p0+p1+fc2_b)*wm + adaptive*(1-wm).
// ---------------------------------------------------------------------------
__global__ __launch_bounds__(256) void combine3(
    float* __restrict__ outp, const float* __restrict__ p1,
    const float* __restrict__ fc2b, const float* __restrict__ h,
    const ushort_t* __restrict__ xnb, const float* __restrict__ a0,
    const float* __restrict__ a1, const float* __restrict__ wm,
    const int* __restrict__ widx)
{
    const size_t idx = (size_t)blockIdx.x * 256 + threadIdx.x;
    const int t   = (int)(idx >> 10);
    const int col = (int)(idx & 1023);
    const float w = wm[t];
    const int sel = widx[t];
    const float base = outp[idx] + p1[idx] + fc2b[col];
    const float ad = (sel == 0) ? a0[idx] : ((sel == 1) ? a1[idx] : b2f(xnb[idx]));
    outp[idx] = h[idx] + base * w + ad * (1.0f - w);
}

// ---------------------------------------------------------------------------
extern "C" void kernel_launch(void* const* d_in, const int* in_sizes, int n_in,
                              void* d_out, int out_size, void* d_ws, size_t ws_size,
                              hipStream_t stream)
{
    const float* x     = (const float*)d_in[0];
    const float* wm    = (const float*)d_in[1];
    const float* wq    = (const float*)d_in[2];
    const float* bq    = (const float*)d_in[3];
    const float* wk    = (const float*)d_in[4];
    const float* bk    = (const float*)d_in[5];
    const float* wv    = (const float*)d_in[6];
    const float* bv    = (const float*)d_in[7];
    const float* wo    = (const float*)d_in[8];
    const float* bo    = (const float*)d_in[9];
    const float* lnq_g = (const float*)d_in[10];
    const float* lnq_b = (const float*)d_in[11];
    const float* lnk_g = (const float*)d_in[12];
    const float* lnk_b = (const float*)d_in[13];
    const float* fc1_w = (const float*)d_in[14];
    const float* fc1_b = (const float*)d_in[15];
    const float* fc2_w = (const float*)d_in[16];
    const float* fc2_b = (const float*)d_in[17];
    const float* lni_g = (const float*)d_in[18];
    const float* lni_b = (const float*)d_in[19];
    const float* lnh_g = (const float*)d_in[20];
    const float* lnh_b = (const float*)d_in[21];
    const float* a256_w1 = (const float*)d_in[22];
    const float* a256_b1 = (const float*)d_in[23];
    const float* a256_w2 = (const float*)d_in[24];
    const float* a256_b2 = (const float*)d_in[25];
    const float* a512_w1 = (const float*)d_in[26];
    const float* a512_b1 = (const float*)d_in[27];
    const float* a512_w2 = (const float*)d_in[28];
    const float* a512_b2 = (const float*)d_in[29];
    const int*   widx    = (const int*)d_in[30];

    float* out = (float*)d_out;

    char* p = (char*)d_ws;
    auto alloc = [&](size_t bytes) { char* r = p; p += (bytes + 255) & ~(size_t)255; return r; };
    float*    qkv   = (float*)   alloc((size_t)MTOK * 3072 * 4);  // a0/a1 alias later
    float*    hb    = (float*)   alloc((size_t)MTOK * 1024 * 4);
    ushort_t* xnb   = (ushort_t*)alloc((size_t)MTOK * 1024 * 2);
    ushort_t* hidb  = (ushort_t*)alloc((size_t)MTOK * 4096 * 2);  // xb/attnb/qh/kh alias
    ushort_t* tA    = (ushort_t*)alloc((size_t)MTOK * 768 * 2);
    ushort_t* WqkvT = (ushort_t*)alloc((size_t)3072 * 1024 * 2);
    ushort_t* WoT   = (ushort_t*)alloc((size_t)1024 * 1024 * 2);
    ushort_t* fc1T  = (ushort_t*)alloc((size_t)4096 * 1024 * 2);
    ushort_t* fc2T  = (ushort_t*)alloc((size_t)1024 * 4096 * 2);
    ushort_t* Wad1T = (ushort_t*)alloc((size_t)768 * 1024 * 2);
    ushort_t* w2aT  = (ushort_t*)alloc((size_t)1024 * 256 * 2);
    ushort_t* w2bT  = (ushort_t*)alloc((size_t)1024 * 512 * 2);
    float*    bqkv  = (float*)   alloc(3072 * 4);
    float*    bad   = (float*)   alloc(768 * 4);
    float*    p1    = (float*)   alloc((size_t)MTOK * 1024 * 4);  // partials / vh alias
    // aliases (lifetimes verified):
    //  xb    = hidb[0 : 4.19M)      dead after qkv GEMM
    //  attnb = hidb[4.19M : 8.39M)  written by attn, dead after wo GEMM
    //  qh/kh = hidb[8.39M : 16.8M)  written by ln_head4, dead after attn
    //  (all dead before fc1 writes hidb)
    //  vh    = p1 region            dead before wo_sk writes p1
    //  a0/a1 = qkv region           qkv dead after ln_head4
    ushort_t* xb    = hidb;
    ushort_t* attnb = hidb + (size_t)MTOK * 1024;
    ushort_t* qh    = hidb + (size_t)MTOK * 2048;
    ushort_t* kh    = hidb + (size_t)MTOK * 3072;
    ushort_t* vh    = (ushort_t*)p1;
    float*    a0    = qkv;
    float*    a1    = qkv + (size_t)MTOK * 1024;

    const dim3 blk(256);

    // ---- prep ----
    prep_bias<<<4, blk, 0, stream>>>(bq, bk, bv, a256_b1, a512_b1, bqkv, bad);
    conv_f2b<<<(MTOK * 1024 / 4 + 255) / 256, blk, 0, stream>>>(x, xb, MTOK * 1024 / 4);
    wtrans4<<<dim3(32, 32, 4), blk, 0, stream>>>(wq, wk, wv, wo,
        WqkvT, WqkvT + 1024 * 1024, WqkvT + 2048 * 1024, WoT);
    wtrans<<<dim3(128, 32), blk, 0, stream>>>(fc1_w, fc1T, 1024, 4096);
    wtrans<<<dim3(32, 128), blk, 0, stream>>>(fc2_w, fc2T, 4096, 1024);
    wtrans<<<dim3(8, 32),   blk, 0, stream>>>(a256_w1, Wad1T, 1024, 256);
    wtrans<<<dim3(16, 32),  blk, 0, stream>>>(a512_w1, Wad1T + 256 * 1024, 1024, 512);
    wtrans<<<dim3(32, 8),   blk, 0, stream>>>(a256_w2, w2aT, 256, 1024);
    wtrans<<<dim3(32, 16),  blk, 0, stream>>>(a512_w2, w2bT, 512, 1024);

    // ---- QKV projection + per-head LN/relayout + MFMA attention ----
    gemm_mfma<0><<<dim3(24, 32), blk, 0, stream>>>(xb, 1024, WqkvT, bqkv, nullptr,
                                                   qkv, nullptr, MTOK, 3072, 1024);
    ln_head4<<<3 * 65536 / 4, blk, 0, stream>>>(qkv, lnq_g, lnq_b, lnk_g, lnk_b,
                                                qh, kh, vh);
    attn_mfma<<<B_ * NH_ * (S_ / 64), blk, 0, stream>>>(qh, kh, vh, attnb);

    // ---- output projection (split-K=2) + fused residual/bias + LN ----
    gemm_wo_sk<<<dim3(8, 32, 2), blk, 0, stream>>>(attnb, WoT, hb, p1);
    ln_token_h<<<MTOK, blk, 0, stream>>>(hb, p1, bo, x, hb, xnb, lni_g, lni_b);

    // ---- base FFN ----
    gemm_mfma<1><<<dim3(32, 32), blk, 0, stream>>>(xnb, 1024, fc1T, fc1_b, nullptr,
                                                   nullptr, hidb, MTOK, 4096, 1024);
    ln_token2<DFF_><<<MTOK, blk, 0, stream>>>(hidb, hidb, lnh_g, lnh_b);
    gemm_fc2_sk<<<dim3(8, 32, 2), blk, 0, stream>>>(hidb, fc2T, out, p1);

    // ---- adapters ----
    gemm_mfma<1><<<dim3(6, 32), blk, 0, stream>>>(xnb, 1024, Wad1T, bad, nullptr,
                                                  nullptr, tA, MTOK, 768, 1024);
    gemm_adapters<<<dim3(8, 32, 2), blk, 0, stream>>>(tA, w2aT, w2bT,
                                                      a256_b2, a512_b2, a0, a1);

    // ---- final routed combine ----
    combine3<<<(int)((size_t)MTOK * 1024 / 256), blk, 0, stream>>>(
        out, p1, fc2_b, hb, xnb, a0, a1, wm, widx);
}

// Round 8
// 344.323 us; speedup vs baseline: 8.1448x; 1.0710x over previous
//
#include <hip/hip_runtime.h>
#include <math.h>

#define B_   2
#define S_   2048
#define DM_  1024
#define NH_  16
#define DH_  64
#define DFF_ 4096
#define WIN_ 256
#define MTOK (B_*S_)   // 4096 tokens

typedef unsigned short ushort_t;
typedef short s16x8 __attribute__((ext_vector_type(8)));
typedef float f32x4 __attribute__((ext_vector_type(4)));

__device__ __forceinline__ float b2f(ushort_t u) {
    union { unsigned int i; float f; } c; c.i = ((unsigned int)u) << 16; return c.f;
}
__device__ __forceinline__ ushort_t f2b(float f) {
    union { float f; unsigned int i; } c; c.f = f;
    unsigned int r = c.i + 0x7fffu + ((c.i >> 16) & 1u);   // RNE
    return (ushort_t)(r >> 16);
}
// tanh-form GELU: |err| vs exact erf-GELU < 3e-3 absolute (<< bf16 noise here)
__device__ __forceinline__ float gelu_fast(float x) {
    const float u = 0.7978845608f * x * fmaf(0.044715f, x * x, 1.0f);
    const float e = __expf(2.0f * u);
    const float t = 1.0f - 2.0f / (e + 1.0f);   // tanh(u)
    return 0.5f * x * (1.0f + t);
}
__device__ __forceinline__ void gload16(const void* g, void* l) {
    __builtin_amdgcn_global_load_lds(
        (const __attribute__((address_space(1))) unsigned int*)g,
        (__attribute__((address_space(3))) unsigned int*)l, 16, 0, 0);
}
// bijective XCD-aware block swizzle — used ONLY for attention (KV L2 locality)
__device__ __forceinline__ int xcd_swz(int wgid, int nwg) {
    const int nx = 8;
    const int q = nwg / nx, r = nwg % nx;
    const int xcd = wgid % nx, lo = wgid / nx;
    const int base = (xcd < r) ? xcd * (q + 1) : r * (q + 1) + (xcd - r) * q;
    return base + lo;
}

// ---------------------------------------------------------------------------
// bf16 MFMA GEMM main loop (m97 structure): 128x128 tile, BK=64, 4 waves.
// Accumulates into acc[4][4]; epilogue is caller-specific.
// ---------------------------------------------------------------------------
__device__ __forceinline__ void gemm_loop(
    const ushort_t* __restrict__ A, int lda,
    const ushort_t* __restrict__ Bt, int ldb,
    int Kc, int bx, int by, f32x4 (&acc)[4][4])
{
    __shared__ __align__(16) ushort_t As[128 * 64];
    __shared__ __align__(16) ushort_t Bs[128 * 64];

    const int tid  = threadIdx.x;
    const int lane = tid & 63;
    const int w    = tid >> 6;
    const int row0 = by * 128;
    const int col0 = bx * 128;

    const int srow = lane >> 3;
    const int sk   = (lane & 7) * 8;
    const int wr   = (w >> 1) * 64;
    const int wc   = (w & 1) * 64;
    const int lr   = lane & 15;
    const int lk   = (lane >> 4) * 8;

    for (int k0 = 0; k0 < Kc; k0 += 64) {
        #pragma unroll
        for (int i = 0; i < 4; ++i) {
            const int c = i * 4 + w;
            const int cr = c * 8 + srow;
            gload16(A  + (size_t)(row0 + cr) * lda + k0 + sk, (char*)As + c * 1024);
            gload16(Bt + (size_t)(col0 + cr) * ldb + k0 + sk, (char*)Bs + c * 1024);
        }
        __syncthreads();
        #pragma unroll
        for (int ks = 0; ks < 2; ++ks) {
            s16x8 af[4], bfr[4];
            #pragma unroll
            for (int mi = 0; mi < 4; ++mi)
                af[mi] = *(const s16x8*)&As[(wr + mi * 16 + lr) * 64 + ks * 32 + lk];
            #pragma unroll
            for (int ni = 0; ni < 4; ++ni)
                bfr[ni] = *(const s16x8*)&Bs[(wc + ni * 16 + lr) * 64 + ks * 32 + lk];
            #pragma unroll
            for (int mi = 0; mi < 4; ++mi)
                #pragma unroll
                for (int ni = 0; ni < 4; ++ni)
                    acc[mi][ni] = __builtin_amdgcn_mfma_f32_16x16x32_bf16(
                        af[mi], bfr[ni], acc[mi][ni], 0, 0, 0);
        }
        __syncthreads();
    }
}

// ---------------------------------------------------------------------------
// QKV GEMM with fused bias + per-head LN + head-major bf16 relayout.
// Wave's 64-col sub-tile == exactly one head; LN reduce = 4 adds + 4 shfl.
// sel (q/k/v) and head are block/wave-uniform. q pre-scaled by 0.125.
// ---------------------------------------------------------------------------
__global__ __launch_bounds__(256) void gemm_qkvln(
    const ushort_t* __restrict__ A, const ushort_t* __restrict__ Bt,
    const float* __restrict__ bias,
    const float* __restrict__ qg, const float* __restrict__ qb,
    const float* __restrict__ kg, const float* __restrict__ kb,
    ushort_t* __restrict__ qh, ushort_t* __restrict__ kh, ushort_t* __restrict__ vh)
{
    f32x4 acc[4][4] = {};
    gemm_loop(A, 1024, Bt, 1024, 1024, blockIdx.x, blockIdx.y, acc);

    const int lane = threadIdx.x & 63;
    const int w    = threadIdx.x >> 6;
    const int wr   = (w >> 1) * 64;
    const int wc   = (w & 1) * 64;
    const int row0 = blockIdx.y * 128;
    const int col0 = blockIdx.x * 128;
    const int crow = (lane >> 4) * 4;
    const int ccol = lane & 15;
    const int sel  = col0 >> 10;                       // 0=q, 1=k, 2=v
    const int hh   = ((col0 + wc) & 1023) >> 6;
    ushort_t* dst = (sel == 0) ? qh : (sel == 1) ? kh : vh;

    #pragma unroll
    for (int mi = 0; mi < 4; ++mi) {
        float val[4][4];                  // [ni][r]
        float s1[4] = {}, sq[4] = {};
        #pragma unroll
        for (int ni = 0; ni < 4; ++ni) {
            const float bc = bias[col0 + wc + ni * 16 + ccol];
            #pragma unroll
            for (int r = 0; r < 4; ++r) {
                const float v = acc[mi][ni][r] + bc;
                val[ni][r] = v;
                s1[r] += v;
                sq[r] = fmaf(v, v, sq[r]);
            }
        }
        if (sel < 2) {
            #pragma unroll
            for (int r = 0; r < 4; ++r) {
                #pragma unroll
                for (int m = 1; m < 16; m <<= 1) {
                    s1[r] += __shfl_xor(s1[r], m);
                    sq[r] += __shfl_xor(sq[r], m);
                }
            }
        }
        #pragma unroll
        for (int r = 0; r < 4; ++r) {
            const int r_abs = row0 + wr + mi * 16 + crow + r;
            const int bb = r_abs >> 11, ss = r_abs & 2047;
            const size_t db = (((size_t)(bb * NH_ + hh)) * S_ + ss) * 64;
            const float mean = s1[r] * 0.015625f;
            const float var  = sq[r] * 0.015625f - mean * mean;
            const float rstd = rsqrtf(var + 1e-5f);
            #pragma unroll
            for (int ni = 0; ni < 4; ++ni) {
                const int d = ni * 16 + ccol;
                float v = val[ni][r];
                if (sel == 0)      v = ((v - mean) * rstd * qg[d] + qb[d]) * 0.125f;
                else if (sel == 1) v = (v - mean) * rstd * kg[d] + kb[d];
                dst[db + d] = f2b(v);
            }
        }
    }
}

// ---------------------------------------------------------------------------
// fc1 + adapter-in fused GEMM: N = 4096 (fc1, gelu->hid) + 768 (adpt, gelu->tA)
// col0 >= 4096 selects adapter region (block-uniform).
// ---------------------------------------------------------------------------
__global__ __launch_bounds__(256) void gemm_fc1ad(
    const ushort_t* __restrict__ A, const ushort_t* __restrict__ Bt,
    const float* __restrict__ bias,
    ushort_t* __restrict__ hid, ushort_t* __restrict__ tA)
{
    f32x4 acc[4][4] = {};
    gemm_loop(A, 1024, Bt, 1024, 1024, blockIdx.x, blockIdx.y, acc);

    const int lane = threadIdx.x & 63;
    const int w    = threadIdx.x >> 6;
    const int wr   = (w >> 1) * 64;
    const int wc   = (w & 1) * 64;
    const int row0 = blockIdx.y * 128;
    const int col0 = blockIdx.x * 128;
    const int crow = (lane >> 4) * 4;
    const int ccol = lane & 15;
    const bool isad = (col0 >= 4096);
    ushort_t* D = isad ? tA : hid;
    const int stride = isad ? 768 : 4096;
    const int cb     = isad ? 4096 : 0;

    #pragma unroll
    for (int ni = 0; ni < 4; ++ni) {
        const int col = col0 + wc + ni * 16 + ccol;
        const float bc = bias[col];
        #pragma unroll
        for (int mi = 0; mi < 4; ++mi) {
            #pragma unroll
            for (int r = 0; r < 4; ++r) {
                const int row = row0 + wr + mi * 16 + crow + r;
                D[(size_t)row * stride + (col - cb)] = f2b(gelu_fast(acc[mi][ni][r] + bc));
            }
        }
    }
}

// ---------------------------------------------------------------------------
// Raw split-K partial GEMM epilogue (wo / fc2): write f32 partials.
// ---------------------------------------------------------------------------
__device__ __forceinline__ void epi_raw(
    f32x4 (&acc)[4][4], float* __restrict__ C, int N, int bx, int by)
{
    const int lane = threadIdx.x & 63;
    const int w    = threadIdx.x >> 6;
    const int wr   = (w >> 1) * 64;
    const int wc   = (w & 1) * 64;
    const int crow = (lane >> 4) * 4;
    const int ccol = lane & 15;
    #pragma unroll
    for (int ni = 0; ni < 4; ++ni) {
        const int col = bx * 128 + wc + ni * 16 + ccol;
        #pragma unroll
        for (int mi = 0; mi < 4; ++mi) {
            #pragma unroll
            for (int r = 0; r < 4; ++r) {
                const int row = by * 128 + wr + mi * 16 + crow + r;
                C[(size_t)row * N + col] = acc[mi][ni][r];
            }
        }
    }
}

__global__ __launch_bounds__(256) void gemm_wo_sk(
    const ushort_t* __restrict__ A, const ushort_t* __restrict__ Wt,
    float* __restrict__ p0, float* __restrict__ p1)
{
    const int z = blockIdx.z;
    f32x4 acc[4][4] = {};
    gemm_loop(A + z * 512, 1024, Wt + z * 512, 1024, 512, blockIdx.x, blockIdx.y, acc);
    epi_raw(acc, z ? p1 : p0, 1024, blockIdx.x, blockIdx.y);
}

__global__ __launch_bounds__(256) void gemm_fc2_sk(
    const ushort_t* __restrict__ A, const ushort_t* __restrict__ Bt,
    float* __restrict__ p0, float* __restrict__ p1)
{
    const int z = blockIdx.z;
    f32x4 acc[4][4] = {};
    gemm_loop(A + z * 2048, 4096, Bt + z * 2048, 4096, 2048, blockIdx.x, blockIdx.y, acc);
    epi_raw(acc, z ? p1 : p0, 1024, blockIdx.x, blockIdx.y);
}

// both adapter out-projections in one dispatch (z selects parameter set)
__global__ __launch_bounds__(256) void gemm_adapters(
    const ushort_t* __restrict__ tA, const ushort_t* __restrict__ w2a,
    const ushort_t* __restrict__ w2b, const float* __restrict__ b2a,
    const float* __restrict__ b2b, float* __restrict__ a0, float* __restrict__ a1)
{
    const int z = blockIdx.z;
    const ushort_t* Ap = z ? tA + 256 : tA;
    const ushort_t* Wp = z ? w2b : w2a;
    const float*    bp = z ? b2b : b2a;
    float*          Cp = z ? a1 : a0;
    const int Kz = z ? 512 : 256;
    f32x4 acc[4][4] = {};
    gemm_loop(Ap, 768, Wp, Kz, Kz, blockIdx.x, blockIdx.y, acc);

    const int lane = threadIdx.x & 63;
    const int w    = threadIdx.x >> 6;
    const int wr   = (w >> 1) * 64;
    const int wc   = (w & 1) * 64;
    const int crow = (lane >> 4) * 4;
    const int ccol = lane & 15;
    #pragma unroll
    for (int ni = 0; ni < 4; ++ni) {
        const int col = blockIdx.x * 128 + wc + ni * 16 + ccol;
        const float bc = bp[col];
        #pragma unroll
        for (int mi = 0; mi < 4; ++mi) {
            #pragma unroll
            for (int r = 0; r < 4; ++r) {
                const int row = blockIdx.y * 128 + wr + mi * 16 + crow + r;
                Cp[(size_t)row * 1024 + col] = acc[mi][ni][r] + bc;
            }
        }
    }
}

// ---------------------------------------------------------------------------
// Weight transpose+convert: W[K,N] f32 -> Wt[N,K] bf16.
// ---------------------------------------------------------------------------
__device__ __forceinline__ void wtrans_core(
    const float* __restrict__ W, ushort_t* __restrict__ Wt, int K, int N,
    int bx, int by)
{
    __shared__ float tile[32][33];
    const int n0 = bx * 32, k0 = by * 32;
    const int tx = threadIdx.x & 31, ty = threadIdx.x >> 5;
    #pragma unroll
    for (int j = 0; j < 4; ++j)
        tile[ty + j * 8][tx] = W[(size_t)(k0 + ty + j * 8) * N + n0 + tx];
    __syncthreads();
    #pragma unroll
    for (int j = 0; j < 4; ++j)
        Wt[(size_t)(n0 + ty + j * 8) * K + k0 + tx] = f2b(tile[tx][ty + j * 8]);
}

__global__ __launch_bounds__(256) void wtrans(
    const float* __restrict__ W, ushort_t* __restrict__ Wt, int K, int N)
{
    wtrans_core(W, Wt, K, N, blockIdx.x, blockIdx.y);
}

__global__ __launch_bounds__(256) void wtrans4(
    const float* w0, const float* w1, const float* w2, const float* w3,
    ushort_t* d0, ushort_t* d1, ushort_t* d2, ushort_t* d3)
{
    const int z = blockIdx.z;
    const float* W = (z == 0) ? w0 : (z == 1) ? w1 : (z == 2) ? w2 : w3;
    ushort_t* Wt   = (z == 0) ? d0 : (z == 1) ? d1 : (z == 2) ? d2 : d3;
    wtrans_core(W, Wt, 1024, 1024, blockIdx.x, blockIdx.y);
}

__global__ __launch_bounds__(256) void conv_f2b(
    const float* __restrict__ in, ushort_t* __restrict__ out, int n4)
{
    const int i = blockIdx.x * 256 + threadIdx.x;
    if (i >= n4) return;
    float4 v = ((const float4*)in)[i];
    ushort4 o; o.x = f2b(v.x); o.y = f2b(v.y); o.z = f2b(v.z); o.w = f2b(v.w);
    ((ushort4*)out)[i] = o;
}

// bqkv[3072] = bq|bk|bv ; bfc1ad[4864] = fc1_b | a256_b1 | a512_b1
__global__ __launch_bounds__(256) void prep_bias(
    const float* bq, const float* bk, const float* bv, const float* fb,
    const float* b1, const float* b2, float* bqkv, float* bfc1ad)
{
    const int t = blockIdx.x * 256 + threadIdx.x;
    if (t < 1024) { bqkv[t] = bq[t]; bqkv[1024 + t] = bk[t]; bqkv[2048 + t] = bv[t]; }
    if (t < 4096)      bfc1ad[t] = fb[t];
    else if (t < 4352) bfc1ad[t] = b1[t - 4096];
    else if (t < 4864) bfc1ad[t] = b2[t - 4352];
}

// ---------------------------------------------------------------------------
// MFMA flash attention. Block = (b, h, 64 queries), 4 waves x 16 q.
// ---------------------------------------------------------------------------
__global__ __launch_bounds__(256) void attn_mfma(
    const ushort_t* __restrict__ qh, const ushort_t* __restrict__ kh,
    const ushort_t* __restrict__ vh, ushort_t* __restrict__ o)
{
    __shared__ __align__(16) ushort_t Ks[64 * 64];
    __shared__ __align__(16) ushort_t Vt[64 * 64];
    __shared__ __align__(16) ushort_t Pl[4 * 16 * 64];

    const int bid = xcd_swz(blockIdx.x, gridDim.x);
    const int qt  = bid & 31;
    const int hh  = (bid >> 5) & 15;
    const int b   = bid >> 9;
    const int wq   = threadIdx.x >> 6;
    const int lane = threadIdx.x & 63;
    const int lg  = lane >> 4;
    const int lq  = lane & 15;

    const int i0  = qt * 64;
    const int iw0 = i0 + wq * 16;
    const int i_l = iw0 + lq;

    const size_t plane = ((size_t)(b * NH_ + hh)) * S_ * 64;

    s16x8 qf[2];
    {
        const ushort_t* qp = qh + plane + (size_t)(iw0 + lq) * 64 + lg * 8;
        qf[0] = *(const s16x8*)(qp);
        qf[1] = *(const s16x8*)(qp + 32);
    }

    f32x4 acc[4] = {};
    float M = -1e30f, L = 0.0f;

    const int jstart = (i0 - WIN_) > 0 ? (i0 - WIN_) : 0;
    const int nt     = (i0 + 64 - jstart) >> 6;

    const int srow0 = threadIdx.x >> 3;
    const int sd0   = (threadIdx.x & 7) * 8;

    for (int t = 0; t < nt; ++t) {
        const int j0 = jstart + t * 64;

        #pragma unroll
        for (int pass = 0; pass < 2; ++pass) {
            const int skey = srow0 + pass * 32;
            const size_t src = plane + (size_t)(j0 + skey) * 64 + sd0;
            s16x8 k8 = *(const s16x8*)(kh + src);
            s16x8 v8 = *(const s16x8*)(vh + src);
            *(s16x8*)&Ks[skey * 64 + (sd0 ^ ((skey & 7) << 3))] = k8;
            #pragma unroll
            for (int e = 0; e < 8; ++e) {
                const int d = sd0 + e;
                Vt[d * 64 + (skey ^ (((d >> 1) & 7) << 3))] = (ushort_t)v8[e];
            }
        }
        __syncthreads();

        f32x4 sc[4];
        #pragma unroll
        for (int kt = 0; kt < 4; ++kt) {
            const int krow = kt * 16 + lq;
            const int swk = (krow & 7) << 3;
            s16x8 k0 = *(const s16x8*)&Ks[krow * 64 + ((lg * 8) ^ swk)];
            s16x8 k1 = *(const s16x8*)&Ks[krow * 64 + ((lg * 8 + 32) ^ swk)];
            f32x4 z = {};
            z = __builtin_amdgcn_mfma_f32_16x16x32_bf16(k0, qf[0], z, 0, 0, 0);
            z = __builtin_amdgcn_mfma_f32_16x16x32_bf16(k1, qf[1], z, 0, 0, 0);
            sc[kt] = z;
        }

        const bool fullv = (j0 + 63 <= iw0) && (iw0 + 15 - j0 <= WIN_);
        if (!fullv) {
            #pragma unroll
            for (int kt = 0; kt < 4; ++kt)
                #pragma unroll
                for (int r = 0; r < 4; ++r) {
                    const int jv = j0 + kt * 16 + lg * 4 + r;
                    const int dd = i_l - jv;
                    const bool ok = (dd >= 0) && (dd <= WIN_);
                    sc[kt][r] = ok ? sc[kt][r] : -1e30f;
                }
        }
        float mx = -1e30f;
        #pragma unroll
        for (int kt = 0; kt < 4; ++kt)
            #pragma unroll
            for (int r = 0; r < 4; ++r) mx = fmaxf(mx, sc[kt][r]);
        mx = fmaxf(mx, __shfl_xor(mx, 16));
        mx = fmaxf(mx, __shfl_xor(mx, 32));
        const float nM = fmaxf(M, mx);
        const float alpha = __expf(M - nM);
        M = nM;
        float ts = 0.0f;
        float ev[16];
        #pragma unroll
        for (int kt = 0; kt < 4; ++kt)
            #pragma unroll
            for (int r = 0; r < 4; ++r) {
                float e = __expf(sc[kt][r] - nM);
                if (!fullv) e = (sc[kt][r] > -1e29f) ? e : 0.0f;
                ev[kt * 4 + r] = e;
                ts += e;
            }
        ts += __shfl_xor(ts, 16);
        ts += __shfl_xor(ts, 32);
        L = L * alpha + ts;

        {
            ushort_t* pw = Pl + wq * 1024;
            const int swq = (lq & 7) << 3;
            #pragma unroll
            for (int kt = 0; kt < 4; ++kt)
                #pragma unroll
                for (int pr = 0; pr < 2; ++pr) {
                    const int key0 = kt * 16 + lg * 4 + pr * 2;
                    const unsigned int pk =
                        (unsigned int)f2b(ev[kt * 4 + pr * 2]) |
                        ((unsigned int)f2b(ev[kt * 4 + pr * 2 + 1]) << 16);
                    *(unsigned int*)&pw[lq * 64 + (key0 ^ swq)] = pk;
                }
        }

        float ar[4];
        #pragma unroll
        for (int r = 0; r < 4; ++r) ar[r] = __shfl(alpha, lg * 4 + r);
        #pragma unroll
        for (int dt = 0; dt < 4; ++dt)
            #pragma unroll
            for (int r = 0; r < 4; ++r) acc[dt][r] *= ar[r];

        {
            const ushort_t* pw = Pl + wq * 1024;
            const int swq = (lq & 7) << 3;
            s16x8 pf0 = *(const s16x8*)&pw[lq * 64 + ((lg * 8) ^ swq)];
            s16x8 pf1 = *(const s16x8*)&pw[lq * 64 + ((lg * 8 + 32) ^ swq)];
            #pragma unroll
            for (int dt = 0; dt < 4; ++dt) {
                const int d = dt * 16 + lq;
                const int swd = ((d >> 1) & 7) << 3;
                s16x8 v0 = *(const s16x8*)&Vt[d * 64 + ((lg * 8) ^ swd)];
                s16x8 v1 = *(const s16x8*)&Vt[d * 64 + ((lg * 8 + 32) ^ swd)];
                acc[dt] = __builtin_amdgcn_mfma_f32_16x16x32_bf16(pf0, v0, acc[dt], 0, 0, 0);
                acc[dt] = __builtin_amdgcn_mfma_f32_16x16x32_bf16(pf1, v1, acc[dt], 0, 0, 0);
            }
        }
        __syncthreads();
    }

    const float inv = 1.0f / L;
    float ir[4];
    #pragma unroll
    for (int r = 0; r < 4; ++r) ir[r] = __shfl(inv, lg * 4 + r);
    #pragma unroll
    for (int dt = 0; dt < 4; ++dt)
        #pragma unroll
        for (int r = 0; r < 4; ++r) {
            const int qq = lg * 4 + r;
            o[((size_t)(b * S_ + iw0 + qq)) * DM_ + hh * 64 + dt * 16 + lq] =
                f2b(acc[dt][r] * ir[r]);
        }
}

// ---------------------------------------------------------------------------
// Fused h-assembly + token LayerNorm (N=1024):
// h = x + p0 + p1 + bo ; hb = h (f32) ; xnb = LN(h)*g+b (bf16).
// ---------------------------------------------------------------------------
__global__ __launch_bounds__(256) void ln_token_h(
    const float* __restrict__ p0, const float* __restrict__ p1,
    const float* __restrict__ bo, const float* __restrict__ x,
    float* __restrict__ hb, ushort_t* __restrict__ xnb,
    const float* __restrict__ g, const float* __restrict__ b)
{
    const int t = blockIdx.x;
    const size_t base = (size_t)t * 1024;
    float vals[4];
    float s = 0.0f, s2 = 0.0f;
    #pragma unroll
    for (int i = 0; i < 4; ++i) {
        const int idx = i * 256 + threadIdx.x;
        const float v = x[base + idx] + p0[base + idx] + p1[base + idx] + bo[idx];
        hb[base + idx] = v;
        vals[i] = v;
        s += v;
        s2 = fmaf(v, v, s2);
    }
    #pragma unroll
    for (int o = 32; o >= 1; o >>= 1) { s += __shfl_xor(s, o); s2 += __shfl_xor(s2, o); }
    __shared__ float rs[4], rq[4];
    const int wid = threadIdx.x >> 6, lane = threadIdx.x & 63;
    if (lane == 0) { rs[wid] = s; rq[wid] = s2; }
    __syncthreads();
    s  = rs[0] + rs[1] + rs[2] + rs[3];
    s2 = rq[0] + rq[1] + rq[2] + rq[3];
    const float mean = s * (1.0f / 1024.0f);
    const float var  = s2 * (1.0f / 1024.0f) - mean * mean;
    const float rstd = rsqrtf(var + 1e-5f);
    #pragma unroll
    for (int i = 0; i < 4; ++i) {
        const int idx = i * 256 + threadIdx.x;
        xnb[base + idx] = f2b((vals[i] - mean) * rstd * g[idx] + b[idx]);
    }
}

// ---------------------------------------------------------------------------
// Token LayerNorm: bf16 in -> bf16 out. One block per token.
// ---------------------------------------------------------------------------
template <int N>
__global__ __launch_bounds__(256) void ln_token2(
    const ushort_t* __restrict__ in, ushort_t* __restrict__ outp,
    const float* __restrict__ g, const float* __restrict__ b)
{
    constexpr int NPT = N / 256;
    const int t = blockIdx.x;
    const ushort_t* row = in + (size_t)t * N;
    float vals[NPT];
    float s = 0.0f, s2 = 0.0f;
    #pragma unroll
    for (int i = 0; i < NPT; ++i) {
        float x = b2f(row[i * 256 + threadIdx.x]);
        vals[i] = x;
        s += x;
        s2 = fmaf(x, x, s2);
    }
    #pragma unroll
    for (int o = 32; o >= 1; o >>= 1) { s += __shfl_xor(s, o); s2 += __shfl_xor(s2, o); }
    __shared__ float rs[4], rq[4];
    const int wid = threadIdx.x >> 6, lane = threadIdx.x & 63;
    if (lane == 0) { rs[wid] = s; rq[wid] = s2; }
    __syncthreads();
    s  = rs[0] + rs[1] + rs[2] + rs[3];
    s2 = rq[0] + rq[1] + rq[2] + rq[3];
    const float mean = s * (1.0f / N);
    const float var  = s2 * (1.0f / N) - mean * mean;
    const float rstd = rsqrtf(var + 1e-5f);
    #pragma unroll
    for (int i = 0; i < NPT; ++i) {
        const int idx = i * 256 + threadIdx.x;
        outp[(size_t)t * N + idx] = f2b((vals[i] - mean) * rstd * g[idx] + b[idx]);
    }
}

// ---------------------------------------------------------------------------
// Final combine: out = h + (p0+p1+fc2_b)*wm + adaptive*(1-wm).
// ---------------------------------------------------------------------------
__global__ __launch_bounds__(256) void combine3(
    float* __restrict__ outp, const float* __restrict__ p1,
    const float* __restrict__ fc2b, const float* __restrict__ h,
    const ushort_t* __restrict__ xnb, const float* __restrict__ a0,
    const float* __restrict__ a1, const float* __restrict__ wm,
    const int* __restrict__ widx)
{
    const size_t idx = (size_t)blockIdx.x * 256 + threadIdx.x;
    const int t   = (int)(idx >> 10);
    const int col = (int)(idx & 1023);
    const float w = wm[t];
    const int sel = widx[t];
    const float base = outp[idx] + p1[idx] + fc2b[col];
    const float ad = (sel == 0) ? a0[idx] : ((sel == 1) ? a1[idx] : b2f(xnb[idx]));
    outp[idx] = h[idx] + base * w + ad * (1.0f - w);
}

// ---------------------------------------------------------------------------
extern "C" void kernel_launch(void* const* d_in, const int* in_sizes, int n_in,
                              void* d_out, int out_size, void* d_ws, size_t ws_size,
                              hipStream_t stream)
{
    const float* x     = (const float*)d_in[0];
    const float* wm    = (const float*)d_in[1];
    const float* wq    = (const float*)d_in[2];
    const float* bq    = (const float*)d_in[3];
    const float* wk    = (const float*)d_in[4];
    const float* bk    = (const float*)d_in[5];
    const float* wv    = (const float*)d_in[6];
    const float* bv    = (const float*)d_in[7];
    const float* wo    = (const float*)d_in[8];
    const float* bo    = (const float*)d_in[9];
    const float* lnq_g = (const float*)d_in[10];
    const float* lnq_b = (const float*)d_in[11];
    const float* lnk_g = (const float*)d_in[12];
    const float* lnk_b = (const float*)d_in[13];
    const float* fc1_w = (const float*)d_in[14];
    const float* fc1_b = (const float*)d_in[15];
    const float* fc2_w = (const float*)d_in[16];
    const float* fc2_b = (const float*)d_in[17];
    const float* lni_g = (const float*)d_in[18];
    const float* lni_b = (const float*)d_in[19];
    const float* lnh_g = (const float*)d_in[20];
    const float* lnh_b = (const float*)d_in[21];
    const float* a256_w1 = (const float*)d_in[22];
    const float* a256_b1 = (const float*)d_in[23];
    const float* a256_w2 = (const float*)d_in[24];
    const float* a256_b2 = (const float*)d_in[25];
    const float* a512_w1 = (const float*)d_in[26];
    const float* a512_b1 = (const float*)d_in[27];
    const float* a512_w2 = (const float*)d_in[28];
    const float* a512_b2 = (const float*)d_in[29];
    const int*   widx    = (const int*)d_in[30];

    float* out = (float*)d_out;

    char* p = (char*)d_ws;
    auto alloc = [&](size_t bytes) { char* r = p; p += (bytes + 255) & ~(size_t)255; return r; };
    float*    ascr  = (float*)   alloc((size_t)MTOK * 2048 * 4);  // a0/a1
    float*    hb    = (float*)   alloc((size_t)MTOK * 1024 * 4);
    ushort_t* xnb   = (ushort_t*)alloc((size_t)MTOK * 1024 * 2);
    ushort_t* hidb  = (ushort_t*)alloc((size_t)MTOK * 4096 * 2);  // xb/attnb/qh/kh alias
    ushort_t* tA    = (ushort_t*)alloc((size_t)MTOK * 768 * 2);
    ushort_t* WqkvT = (ushort_t*)alloc((size_t)3072 * 1024 * 2);
    ushort_t* WoT   = (ushort_t*)alloc((size_t)1024 * 1024 * 2);
    ushort_t* fc1adT= (ushort_t*)alloc((size_t)4864 * 1024 * 2);  // fc1 + adapter-in
    ushort_t* fc2T  = (ushort_t*)alloc((size_t)1024 * 4096 * 2);
    ushort_t* w2aT  = (ushort_t*)alloc((size_t)1024 * 256 * 2);
    ushort_t* w2bT  = (ushort_t*)alloc((size_t)1024 * 512 * 2);
    float*    bqkv  = (float*)   alloc(3072 * 4);
    float*    bfc1ad= (float*)   alloc(4864 * 4);
    float*    p1    = (float*)   alloc((size_t)MTOK * 1024 * 4);  // partials / vh alias
    // aliases (lifetimes verified):
    //  xb    = hidb[0 : 4.19M)      read by qkvln, dead after
    //  attnb = hidb[4.19M : 8.39M)  written by attn, dead after wo_sk
    //  qh/kh = hidb[8.39M : 16.8M)  written by qkvln epilogue, dead after attn
    //  (all dead before fc1ad writes hidb)
    //  vh    = p1 region            dead before wo_sk writes p1
    //  a0/a1 = ascr
    ushort_t* xb    = hidb;
    ushort_t* attnb = hidb + (size_t)MTOK * 1024;
    ushort_t* qh    = hidb + (size_t)MTOK * 2048;
    ushort_t* kh    = hidb + (size_t)MTOK * 3072;
    ushort_t* vh    = (ushort_t*)p1;
    float*    a0    = ascr;
    float*    a1    = ascr + (size_t)MTOK * 1024;

    const dim3 blk(256);

    // ---- prep ----
    prep_bias<<<20, blk, 0, stream>>>(bq, bk, bv, fc1_b, a256_b1, a512_b1,
                                      bqkv, bfc1ad);
    conv_f2b<<<(MTOK * 1024 / 4 + 255) / 256, blk, 0, stream>>>(x, xb, MTOK * 1024 / 4);
    wtrans4<<<dim3(32, 32, 4), blk, 0, stream>>>(wq, wk, wv, wo,
        WqkvT, WqkvT + 1024 * 1024, WqkvT + 2048 * 1024, WoT);
    wtrans<<<dim3(128, 32), blk, 0, stream>>>(fc1_w, fc1adT, 1024, 4096);
    wtrans<<<dim3(8, 32),   blk, 0, stream>>>(a256_w1, fc1adT + (size_t)4096 * 1024, 1024, 256);
    wtrans<<<dim3(16, 32),  blk, 0, stream>>>(a512_w1, fc1adT + (size_t)4352 * 1024, 1024, 512);
    wtrans<<<dim3(32, 128), blk, 0, stream>>>(fc2_w, fc2T, 4096, 1024);
    wtrans<<<dim3(32, 8),   blk, 0, stream>>>(a256_w2, w2aT, 256, 1024);
    wtrans<<<dim3(32, 16),  blk, 0, stream>>>(a512_w2, w2bT, 512, 1024);

    // ---- QKV GEMM + fused per-head LN/relayout, then MFMA attention ----
    gemm_qkvln<<<dim3(24, 32), blk, 0, stream>>>(xb, WqkvT, bqkv,
        lnq_g, lnq_b, lnk_g, lnk_b, qh, kh, vh);
    attn_mfma<<<B_ * NH_ * (S_ / 64), blk, 0, stream>>>(qh, kh, vh, attnb);

    // ---- output projection (split-K=2) + fused residual/bias + LN ----
    gemm_wo_sk<<<dim3(8, 32, 2), blk, 0, stream>>>(attnb, WoT, hb, p1);
    ln_token_h<<<MTOK, blk, 0, stream>>>(hb, p1, bo, x, hb, xnb, lni_g, lni_b);

    // ---- fc1 + adapter-in fused ----
    gemm_fc1ad<<<dim3(38, 32), blk, 0, stream>>>(xnb, fc1adT, bfc1ad, hidb, tA);
    ln_token2<DFF_><<<MTOK, blk, 0, stream>>>(hidb, hidb, lnh_g, lnh_b);
    gemm_fc2_sk<<<dim3(8, 32, 2), blk, 0, stream>>>(hidb, fc2T, out, p1);

    // ---- adapter out-projections ----
    gemm_adapters<<<dim3(8, 32, 2), blk, 0, stream>>>(tA, w2aT, w2bT,
                                                      a256_b2, a512_b2, a0, a1);

    // ---- final routed combine ----
    combine3<<<(int)((size_t)MTOK * 1024 / 256), blk, 0, stream>>>(
        out, p1, fc2_b, hb, xnb, a0, a1, wm, widx);
}